// Round 1
// baseline (380.018 us; speedup 1.0000x reference)
//
#include <hip/hip_runtime.h>
#include <hip/hip_bf16.h>
#include <math.h>

#define BB 2
#define CC 256
#define GG 32
#define NN 4096
#define CPG 8
#define EPSF 1e-6f

typedef _Float16 f16x8 __attribute__((ext_vector_type(8)));
typedef float f32x4 __attribute__((ext_vector_type(4)));

static __device__ __forceinline__ unsigned short f2h_bits(float f) {
    _Float16 h = (_Float16)f;
    return __builtin_bit_cast(unsigned short, h);
}

// ---------------- Kernel 1: GroupNorm stats (mean, rstd) per (b, g) ----------------
__global__ __launch_bounds__(256) void gn_stats_kernel(
    const float* __restrict__ x, float* __restrict__ stats)
{
    int g = blockIdx.x, b = blockIdx.y;
    const float* base = x + ((size_t)b * CC + (size_t)g * CPG) * NN;
    int t = threadIdx.x;
    float s = 0.f, ss = 0.f;
    // group slab is contiguous: CPG*NN = 32768 floats = 8192 float4
    for (int idx = t; idx < 8192; idx += 256) {
        float4 v4 = ((const float4*)base)[idx];
        s  += v4.x + v4.y + v4.z + v4.w;
        ss += v4.x*v4.x + v4.y*v4.y + v4.z*v4.z + v4.w*v4.w;
    }
    for (int off = 32; off; off >>= 1) {
        s  += __shfl_down(s,  off);
        ss += __shfl_down(ss, off);
    }
    __shared__ float red[8];
    int wid = t >> 6;
    if ((t & 63) == 0) { red[wid*2] = s; red[wid*2+1] = ss; }
    __syncthreads();
    if (t == 0) {
        float S  = red[0] + red[2] + red[4] + red[6];
        float SS = red[1] + red[3] + red[5] + red[7];
        float mean = S / 32768.f;
        float var  = SS / 32768.f - mean * mean;
        float rstd = rsqrtf(var + EPSF);
        stats[(b*GG + g)*2]     = mean;
        stats[(b*GG + g)*2 + 1] = rstd;
    }
}

// ------------- Kernel 2: apply GN, write h_T (b, n, c) as fp16 (transposed) -------------
__global__ __launch_bounds__(256) void gn_apply_kernel(
    const float* __restrict__ x, const float* __restrict__ sc,
    const float* __restrict__ bi, const float* __restrict__ stats,
    unsigned short* __restrict__ hT)
{
    int b  = blockIdx.y;
    int i0 = blockIdx.x * 64;
    int t  = threadIdx.x;
    __shared__ unsigned short tile[64][264];  // 64 i x 256 c, pad 8
    __shared__ float s_mean[GG], s_rstd[GG], s_sc[CC], s_bi[CC];
    if (t < GG) { s_mean[t] = stats[(b*GG + t)*2]; s_rstd[t] = stats[(b*GG + t)*2 + 1]; }
    s_sc[t] = sc[t];
    s_bi[t] = bi[t];
    __syncthreads();
    int i4 = (t & 15) * 4;
    int cb = t >> 4;
    for (int k = 0; k < 16; k++) {
        int c = cb + k * 16;
        float4 v4 = *(const float4*)(x + ((size_t)b*CC + c)*NN + i0 + i4);
        float a = s_rstd[c >> 3] * s_sc[c];
        float d = s_bi[c] - s_mean[c >> 3] * a;
        tile[i4+0][c] = f2h_bits(v4.x * a + d);
        tile[i4+1][c] = f2h_bits(v4.y * a + d);
        tile[i4+2][c] = f2h_bits(v4.z * a + d);
        tile[i4+3][c] = f2h_bits(v4.w * a + d);
    }
    __syncthreads();
    int row = t >> 2, c0 = (t & 3) * 64;
    unsigned short* dst = hT + (size_t)b*NN*CC + (size_t)(i0 + row)*CC + c0;
    for (int k = 0; k < 8; k++) {
        uint4 u = *(const uint4*)&tile[row][c0 + k*8];
        *(uint4*)(dst + k*8) = u;
    }
}

// ------------- Kernel 3: q,k projections: qT/kT (b, n, c) fp16, q pre-scaled -------------
__global__ __launch_bounds__(256) void proj_qk_kernel(
    const unsigned short* __restrict__ hT,
    const float* __restrict__ wq, const float* __restrict__ bq,
    const float* __restrict__ wk, const float* __restrict__ bk,
    unsigned short* __restrict__ qT, unsigned short* __restrict__ kT)
{
    int b = blockIdx.z >> 1, p = blockIdx.z & 1;
    const float* wgt  = p ? wk : wq;
    const float* bias = p ? bk : bq;
    unsigned short* out = p ? kT : qT;
    float oscale = p ? 1.0f : 0.0625f;  // q pre-scaled by c^-0.5
    int i0 = blockIdx.x * 64, o0 = blockIdx.y * 64;
    int lane = threadIdx.x & 63, wid = threadIdx.x >> 6;
    int col = lane & 15, grp = lane >> 4;
    int ow = o0 + wid * 16;
    const unsigned short* hb = hT + (size_t)b*NN*CC;
    f32x4 acc[4];
    for (int it = 0; it < 4; it++) acc[it] = (f32x4){0.f,0.f,0.f,0.f};
    for (int ck = 0; ck < 8; ck++) {
        const float* w8 = wgt + (size_t)(ow + col)*CC + ck*32 + grp*8;
        f16x8 af;
        for (int j = 0; j < 8; j++) af[j] = (_Float16)w8[j];
        for (int it = 0; it < 4; it++) {
            f16x8 bf = *(const f16x8*)(hb + (size_t)(i0 + it*16 + col)*CC + ck*32 + grp*8);
            acc[it] = __builtin_amdgcn_mfma_f32_16x16x32_f16(af, bf, acc[it], 0, 0, 0);
        }
    }
    int obase = ow + grp * 4;
    float b0 = bias[obase], b1 = bias[obase+1], b2 = bias[obase+2], b3 = bias[obase+3];
    for (int it = 0; it < 4; it++) {
        int i = i0 + it*16 + col;
        union { _Float16 h[4]; uint2 u; } pk;
        pk.h[0] = (_Float16)((acc[it][0] + b0) * oscale);
        pk.h[1] = (_Float16)((acc[it][1] + b1) * oscale);
        pk.h[2] = (_Float16)((acc[it][2] + b2) * oscale);
        pk.h[3] = (_Float16)((acc[it][3] + b3) * oscale);
        *(uint2*)(out + (size_t)b*NN*CC + (size_t)i*CC + obase) = pk.u;
    }
}

// ------------- Kernel 4: v projection: v (b, c, n) fp16 -------------
__global__ __launch_bounds__(256) void proj_v_kernel(
    const unsigned short* __restrict__ hT,
    const float* __restrict__ wv, const float* __restrict__ bv,
    unsigned short* __restrict__ vC)
{
    int b = blockIdx.z;
    int i0 = blockIdx.x * 64, o0 = blockIdx.y * 64;
    int lane = threadIdx.x & 63, wid = threadIdx.x >> 6;
    int col = lane & 15, grp = lane >> 4;
    int ibase = i0 + wid * 16;
    const unsigned short* hb = hT + (size_t)b*NN*CC;
    f32x4 acc[4];
    for (int ot = 0; ot < 4; ot++) acc[ot] = (f32x4){0.f,0.f,0.f,0.f};
    for (int ck = 0; ck < 8; ck++) {
        f16x8 af = *(const f16x8*)(hb + (size_t)(ibase + col)*CC + ck*32 + grp*8);
        for (int ot = 0; ot < 4; ot++) {
            const float* w8 = wv + (size_t)(o0 + ot*16 + col)*CC + ck*32 + grp*8;
            f16x8 bf;
            for (int j = 0; j < 8; j++) bf[j] = (_Float16)w8[j];
            acc[ot] = __builtin_amdgcn_mfma_f32_16x16x32_f16(af, bf, acc[ot], 0, 0, 0);
        }
    }
    int iw = ibase + grp * 4;
    for (int ot = 0; ot < 4; ot++) {
        int o = o0 + ot*16 + col;
        float bo = bv[o];
        union { _Float16 h[4]; uint2 u; } pk;
        pk.h[0] = (_Float16)(acc[ot][0] + bo);
        pk.h[1] = (_Float16)(acc[ot][1] + bo);
        pk.h[2] = (_Float16)(acc[ot][2] + bo);
        pk.h[3] = (_Float16)(acc[ot][3] + bo);
        *(uint2*)(vC + (size_t)b*CC*NN + (size_t)o*NN + iw) = pk.u;
    }
}

// ------------- Kernel 5: flash attention, 1 wave / 16 queries -------------
__global__ __launch_bounds__(64) void attn_kernel(
    const unsigned short* __restrict__ qT,
    const unsigned short* __restrict__ kT,
    const unsigned short* __restrict__ vC,
    unsigned short* __restrict__ aT)
{
    int b  = blockIdx.y;
    int i0 = blockIdx.x * 16;
    int lane = threadIdx.x;
    int col = lane & 15, grp = lane >> 4;
    const unsigned short* qb = qT + (size_t)b*NN*CC;
    const unsigned short* kb = kT + (size_t)b*NN*CC;
    const unsigned short* vb = vC + (size_t)b*CC*NN;

    f16x8 qf[8];
    for (int ck = 0; ck < 8; ck++)
        qf[ck] = *(const f16x8*)(qb + (size_t)(i0 + col)*CC + ck*32 + grp*8);

    f32x4 O[16];
    for (int ck = 0; ck < 16; ck++) O[ck] = (f32x4){0.f,0.f,0.f,0.f};
    float m[4]    = {-1e30f, -1e30f, -1e30f, -1e30f};
    float lsum[4] = {0.f, 0.f, 0.f, 0.f};

    __shared__ unsigned short plds[16 * 40];

    for (int j0 = 0; j0 < NN; j0 += 32) {
        f32x4 s0 = (f32x4){0.f,0.f,0.f,0.f};
        f32x4 s1 = (f32x4){0.f,0.f,0.f,0.f};
        for (int ck = 0; ck < 8; ck++) {
            f16x8 k0 = *(const f16x8*)(kb + (size_t)(j0      + col)*CC + ck*32 + grp*8);
            f16x8 k1 = *(const f16x8*)(kb + (size_t)(j0 + 16 + col)*CC + ck*32 + grp*8);
            s0 = __builtin_amdgcn_mfma_f32_16x16x32_f16(qf[ck], k0, s0, 0, 0, 0);
            s1 = __builtin_amdgcn_mfma_f32_16x16x32_f16(qf[ck], k1, s1, 0, 0, 0);
        }
        // online softmax; row r of this lane-group = query (grp*4 + r)
        float fscale[4];
        for (int r = 0; r < 4; r++) {
            float mx = fmaxf(s0[r], s1[r]);
            mx = fmaxf(mx, __shfl_xor(mx, 1));
            mx = fmaxf(mx, __shfl_xor(mx, 2));
            mx = fmaxf(mx, __shfl_xor(mx, 4));
            mx = fmaxf(mx, __shfl_xor(mx, 8));
            float mn = fmaxf(m[r], mx);
            float f  = __expf(m[r] - mn);
            m[r] = mn;
            float p0 = __expf(s0[r] - mn);
            float p1 = __expf(s1[r] - mn);
            s0[r] = p0; s1[r] = p1;
            float ps = p0 + p1;
            ps += __shfl_xor(ps, 1);
            ps += __shfl_xor(ps, 2);
            ps += __shfl_xor(ps, 4);
            ps += __shfl_xor(ps, 8);
            lsum[r] = lsum[r] * f + ps;
            fscale[r] = f;
        }
        for (int ck = 0; ck < 16; ck++) {
            O[ck][0] *= fscale[0];
            O[ck][1] *= fscale[1];
            O[ck][2] *= fscale[2];
            O[ck][3] *= fscale[3];
        }
        // repack P (f32 S-frag layout) -> fp16 A-frag layout via LDS
        for (int r = 0; r < 4; r++) {
            plds[(grp*4 + r)*40 + col]      = f2h_bits(s0[r]);
            plds[(grp*4 + r)*40 + 16 + col] = f2h_bits(s1[r]);
        }
        __syncthreads();
        f16x8 pf = *(const f16x8*)(plds + col*40 + grp*8);
        // PV: O[q][c] += P(16x32) * V^T(32x16 per c-chunk)
        for (int ck = 0; ck < 16; ck++) {
            f16x8 vf = *(const f16x8*)(vb + (size_t)(ck*16 + col)*NN + j0 + grp*8);
            O[ck] = __builtin_amdgcn_mfma_f32_16x16x32_f16(pf, vf, O[ck], 0, 0, 0);
        }
        __syncthreads();
    }
    float inv[4];
    for (int r = 0; r < 4; r++) inv[r] = 1.f / lsum[r];
    unsigned short* ab = aT + (size_t)b*NN*CC;
    for (int ck = 0; ck < 16; ck++)
        for (int r = 0; r < 4; r++)
            ab[(size_t)(i0 + grp*4 + r)*CC + ck*16 + col] = f2h_bits(O[ck][r] * inv[r]);
}

// ------------- Kernel 6: output projection + bias + residual (fp32 out) -------------
__global__ __launch_bounds__(256) void proj_out_kernel(
    const unsigned short* __restrict__ aT,
    const float* __restrict__ wp, const float* __restrict__ bp,
    const float* __restrict__ x, float* __restrict__ out)
{
    int b = blockIdx.z;
    int i0 = blockIdx.x * 64, o0 = blockIdx.y * 64;
    int lane = threadIdx.x & 63, wid = threadIdx.x >> 6;
    int col = lane & 15, grp = lane >> 4;
    int ibase = i0 + wid * 16;
    const unsigned short* ab = aT + (size_t)b*NN*CC;
    f32x4 acc[4];
    for (int ot = 0; ot < 4; ot++) acc[ot] = (f32x4){0.f,0.f,0.f,0.f};
    for (int ck = 0; ck < 8; ck++) {
        f16x8 af = *(const f16x8*)(ab + (size_t)(ibase + col)*CC + ck*32 + grp*8);
        for (int ot = 0; ot < 4; ot++) {
            const float* w8 = wp + (size_t)(o0 + ot*16 + col)*CC + ck*32 + grp*8;
            f16x8 bf;
            for (int j = 0; j < 8; j++) bf[j] = (_Float16)w8[j];
            acc[ot] = __builtin_amdgcn_mfma_f32_16x16x32_f16(af, bf, acc[ot], 0, 0, 0);
        }
    }
    int iw = ibase + grp * 4;
    for (int ot = 0; ot < 4; ot++) {
        int o = o0 + ot*16 + col;
        float bo = bp[o];
        size_t base = (size_t)b*CC*NN + (size_t)o*NN + iw;
        float4 x4 = *(const float4*)(x + base);
        float4 r;
        r.x = x4.x + acc[ot][0] + bo;
        r.y = x4.y + acc[ot][1] + bo;
        r.z = x4.z + acc[ot][2] + bo;
        r.w = x4.w + acc[ot][3] + bo;
        *(float4*)(out + base) = r;
    }
}

extern "C" void kernel_launch(void* const* d_in, const int* in_sizes, int n_in,
                              void* d_out, int out_size, void* d_ws, size_t ws_size,
                              hipStream_t stream) {
    const float* x  = (const float*)d_in[0];
    const float* gs = (const float*)d_in[1];
    const float* gb = (const float*)d_in[2];
    const float* wq = (const float*)d_in[3];
    const float* bq = (const float*)d_in[4];
    const float* wk = (const float*)d_in[5];
    const float* bk = (const float*)d_in[6];
    const float* wv = (const float*)d_in[7];
    const float* bv = (const float*)d_in[8];
    const float* wp = (const float*)d_in[9];
    const float* bp = (const float*)d_in[10];
    float* out = (float*)d_out;

    char* ws = (char*)d_ws;
    const size_t sz = (size_t)BB * NN * CC * sizeof(unsigned short);  // 4 MB
    unsigned short* hT = (unsigned short*)(ws);
    unsigned short* qT = (unsigned short*)(ws + sz);
    unsigned short* kT = (unsigned short*)(ws + 2*sz);
    unsigned short* vC = (unsigned short*)(ws + 3*sz);
    unsigned short* aT = (unsigned short*)(ws + 4*sz);
    float* stats = (float*)(ws + 5*sz);

    gn_stats_kernel<<<dim3(GG, BB), 256, 0, stream>>>(x, stats);
    gn_apply_kernel<<<dim3(NN/64, BB), 256, 0, stream>>>(x, gs, gb, stats, hT);
    proj_qk_kernel<<<dim3(NN/64, CC/64, 2*BB), 256, 0, stream>>>(hT, wq, bq, wk, bk, qT, kT);
    proj_v_kernel<<<dim3(NN/64, CC/64, BB), 256, 0, stream>>>(hT, wv, bv, vC);
    attn_kernel<<<dim3(NN/16, BB), 64, 0, stream>>>(qT, kT, vC, aT);
    proj_out_kernel<<<dim3(NN/64, CC/64, BB), 256, 0, stream>>>(aT, wp, bp, x, out);
}

// Round 2
// 235.077 us; speedup vs baseline: 1.6166x; 1.6166x over previous
//
#include <hip/hip_runtime.h>
#include <hip/hip_bf16.h>
#include <math.h>

#define BB 2
#define CC 256
#define GG 32
#define NN 4096
#define CPG 8
#define EPSF 1e-6f
#define QB 32          // queries per block (attn)
#define NWAVE 8        // waves per attn block
#define JW (NN / NWAVE) // j-range per wave

typedef _Float16 f16x8 __attribute__((ext_vector_type(8)));
typedef float f32x4 __attribute__((ext_vector_type(4)));

static __device__ __forceinline__ unsigned short f2h_bits(float f) {
    _Float16 h = (_Float16)f;
    return __builtin_bit_cast(unsigned short, h);
}

// ---------------- Kernel 0: convert weights to fp16 (wq pre-scaled by c^-0.5) ----------------
__global__ __launch_bounds__(256) void prep_w16_kernel(
    const float* __restrict__ wq, const float* __restrict__ wk,
    const float* __restrict__ wv, const float* __restrict__ wp,
    unsigned short* __restrict__ w16)
{
    int m = blockIdx.y;
    const float* src = (m == 0) ? wq : (m == 1) ? wk : (m == 2) ? wv : wp;
    float scale = (m == 0) ? 0.0625f : 1.0f;
    int idx = blockIdx.x * 256 + threadIdx.x;   // unit = 4 floats
    float4 v = ((const float4*)src)[idx];
    union { _Float16 h[4]; uint2 u; } pk;
    pk.h[0] = (_Float16)(v.x * scale);
    pk.h[1] = (_Float16)(v.y * scale);
    pk.h[2] = (_Float16)(v.z * scale);
    pk.h[3] = (_Float16)(v.w * scale);
    *(uint2*)(w16 + (size_t)m * CC * CC + (size_t)idx * 4) = pk.u;
}

// ---------------- Kernel 1: GroupNorm stats (mean, rstd) per (b, g) ----------------
__global__ __launch_bounds__(256) void gn_stats_kernel(
    const float* __restrict__ x, float* __restrict__ stats)
{
    int g = blockIdx.x, b = blockIdx.y;
    const float* base = x + ((size_t)b * CC + (size_t)g * CPG) * NN;
    int t = threadIdx.x;
    float s = 0.f, ss = 0.f;
    for (int idx = t; idx < 8192; idx += 256) {
        float4 v4 = ((const float4*)base)[idx];
        s  += v4.x + v4.y + v4.z + v4.w;
        ss += v4.x*v4.x + v4.y*v4.y + v4.z*v4.z + v4.w*v4.w;
    }
    for (int off = 32; off; off >>= 1) {
        s  += __shfl_down(s,  off);
        ss += __shfl_down(ss, off);
    }
    __shared__ float red[8];
    int wid = t >> 6;
    if ((t & 63) == 0) { red[wid*2] = s; red[wid*2+1] = ss; }
    __syncthreads();
    if (t == 0) {
        float S  = red[0] + red[2] + red[4] + red[6];
        float SS = red[1] + red[3] + red[5] + red[7];
        float mean = S / 32768.f;
        float var  = SS / 32768.f - mean * mean;
        float rstd = rsqrtf(var + EPSF);
        stats[(b*GG + g)*2]     = mean;
        stats[(b*GG + g)*2 + 1] = rstd;
    }
}

// ------------- Kernel 2: apply GN, write h_T (b, n, c) as fp16 (transposed) -------------
__global__ __launch_bounds__(256) void gn_apply_kernel(
    const float* __restrict__ x, const float* __restrict__ sc,
    const float* __restrict__ bi, const float* __restrict__ stats,
    unsigned short* __restrict__ hT)
{
    int b  = blockIdx.y;
    int i0 = blockIdx.x * 64;
    int t  = threadIdx.x;
    __shared__ unsigned short tile[64][264];
    __shared__ float s_mean[GG], s_rstd[GG], s_sc[CC], s_bi[CC];
    if (t < GG) { s_mean[t] = stats[(b*GG + t)*2]; s_rstd[t] = stats[(b*GG + t)*2 + 1]; }
    s_sc[t] = sc[t];
    s_bi[t] = bi[t];
    __syncthreads();
    int i4 = (t & 15) * 4;
    int cb = t >> 4;
    for (int k = 0; k < 16; k++) {
        int c = cb + k * 16;
        float4 v4 = *(const float4*)(x + ((size_t)b*CC + c)*NN + i0 + i4);
        float a = s_rstd[c >> 3] * s_sc[c];
        float d = s_bi[c] - s_mean[c >> 3] * a;
        tile[i4+0][c] = f2h_bits(v4.x * a + d);
        tile[i4+1][c] = f2h_bits(v4.y * a + d);
        tile[i4+2][c] = f2h_bits(v4.z * a + d);
        tile[i4+3][c] = f2h_bits(v4.w * a + d);
    }
    __syncthreads();
    int row = t >> 2, c0 = (t & 3) * 64;
    unsigned short* dst = hT + (size_t)b*NN*CC + (size_t)(i0 + row)*CC + c0;
    for (int k = 0; k < 8; k++) {
        uint4 u = *(const uint4*)&tile[row][c0 + k*8];
        *(uint4*)(dst + k*8) = u;
    }
}

// ------------- Kernel 3: q,k projections (fp16 weights) -------------
__global__ __launch_bounds__(256) void proj_qk_kernel(
    const unsigned short* __restrict__ hT,
    const unsigned short* __restrict__ w16,
    const float* __restrict__ bq, const float* __restrict__ bk,
    unsigned short* __restrict__ qT, unsigned short* __restrict__ kT)
{
    int b = blockIdx.z >> 1, p = blockIdx.z & 1;
    const unsigned short* wgt = w16 + (size_t)p * CC * CC;  // slab 0 = wq(scaled), 1 = wk
    const float* bias = p ? bk : bq;
    unsigned short* out = p ? kT : qT;
    float oscale = p ? 1.0f : 0.0625f;  // bias scale only; weights pre-scaled
    int i0 = blockIdx.x * 64, o0 = blockIdx.y * 64;
    int lane = threadIdx.x & 63, wid = threadIdx.x >> 6;
    int col = lane & 15, grp = lane >> 4;
    int ow = o0 + wid * 16;
    const unsigned short* hb = hT + (size_t)b*NN*CC;
    f32x4 acc[4];
    for (int it = 0; it < 4; it++) acc[it] = (f32x4){0.f,0.f,0.f,0.f};
    for (int ck = 0; ck < 8; ck++) {
        f16x8 af = *(const f16x8*)(wgt + (size_t)(ow + col)*CC + ck*32 + grp*8);
        for (int it = 0; it < 4; it++) {
            f16x8 bf = *(const f16x8*)(hb + (size_t)(i0 + it*16 + col)*CC + ck*32 + grp*8);
            acc[it] = __builtin_amdgcn_mfma_f32_16x16x32_f16(af, bf, acc[it], 0, 0, 0);
        }
    }
    int obase = ow + grp * 4;
    float b0 = bias[obase]*oscale, b1 = bias[obase+1]*oscale,
          b2 = bias[obase+2]*oscale, b3 = bias[obase+3]*oscale;
    for (int it = 0; it < 4; it++) {
        int i = i0 + it*16 + col;
        union { _Float16 h[4]; uint2 u; } pk;
        pk.h[0] = (_Float16)(acc[it][0] + b0);
        pk.h[1] = (_Float16)(acc[it][1] + b1);
        pk.h[2] = (_Float16)(acc[it][2] + b2);
        pk.h[3] = (_Float16)(acc[it][3] + b3);
        *(uint2*)(out + (size_t)b*NN*CC + (size_t)i*CC + obase) = pk.u;
    }
}

// ------------- Kernel 4: v projection: v (b, c, n) fp16 (fp16 weights) -------------
__global__ __launch_bounds__(256) void proj_v_kernel(
    const unsigned short* __restrict__ hT,
    const unsigned short* __restrict__ wv16, const float* __restrict__ bv,
    unsigned short* __restrict__ vC)
{
    int b = blockIdx.z;
    int i0 = blockIdx.x * 64, o0 = blockIdx.y * 64;
    int lane = threadIdx.x & 63, wid = threadIdx.x >> 6;
    int col = lane & 15, grp = lane >> 4;
    int ibase = i0 + wid * 16;
    const unsigned short* hb = hT + (size_t)b*NN*CC;
    f32x4 acc[4];
    for (int ot = 0; ot < 4; ot++) acc[ot] = (f32x4){0.f,0.f,0.f,0.f};
    for (int ck = 0; ck < 8; ck++) {
        f16x8 af = *(const f16x8*)(hb + (size_t)(ibase + col)*CC + ck*32 + grp*8);
        for (int ot = 0; ot < 4; ot++) {
            f16x8 bf = *(const f16x8*)(wv16 + (size_t)(o0 + ot*16 + col)*CC + ck*32 + grp*8);
            acc[ot] = __builtin_amdgcn_mfma_f32_16x16x32_f16(af, bf, acc[ot], 0, 0, 0);
        }
    }
    int iw = ibase + grp * 4;
    for (int ot = 0; ot < 4; ot++) {
        int o = o0 + ot*16 + col;
        float bo = bv[o];
        union { _Float16 h[4]; uint2 u; } pk;
        pk.h[0] = (_Float16)(acc[ot][0] + bo);
        pk.h[1] = (_Float16)(acc[ot][1] + bo);
        pk.h[2] = (_Float16)(acc[ot][2] + bo);
        pk.h[3] = (_Float16)(acc[ot][3] + bo);
        *(uint2*)(vC + (size_t)b*CC*NN + (size_t)o*NN + iw) = pk.u;
    }
}

// ------------- Kernel 5: flash attention, 8 waves/block, in-block j-split + LDS merge -------------
__global__ __launch_bounds__(512, 2) void attn_kernel(
    const unsigned short* __restrict__ qT,
    const unsigned short* __restrict__ kT,
    const unsigned short* __restrict__ vC,
    unsigned short* __restrict__ aT)
{
    int b  = blockIdx.y;
    int i0 = blockIdx.x * QB;
    int tid  = threadIdx.x;
    int w    = tid >> 6;
    int lane = tid & 63;
    int col = lane & 15, grp = lane >> 4;

    __shared__ unsigned short SM[NWAVE][QB][260];   // per-wave normalized partial O (fp16)
    __shared__ float2 MLs[NWAVE][QB];               // per-wave (m, l)
    __shared__ unsigned short plds[NWAVE][2][16][42];

    const unsigned short* qb = qT + (size_t)b*NN*CC;
    const unsigned short* kb = kT + (size_t)b*NN*CC;
    const unsigned short* vb = vC + (size_t)b*CC*NN;

    f16x8 qf[2][8];
    for (int t = 0; t < 2; t++)
        for (int ck = 0; ck < 8; ck++)
            qf[t][ck] = *(const f16x8*)(qb + (size_t)(i0 + t*16 + col)*CC + ck*32 + grp*8);

    f32x4 O[2][16];
    for (int t = 0; t < 2; t++)
        for (int ck = 0; ck < 16; ck++) O[t][ck] = (f32x4){0.f,0.f,0.f,0.f};
    float m[8], l[8];
    for (int r = 0; r < 8; r++) { m[r] = -1e30f; l[r] = 0.f; }

    int j_lo = w * JW, j_hi = j_lo + JW;
    for (int j0 = j_lo; j0 < j_hi; j0 += 32) {
        f32x4 s[2][2];
        s[0][0] = (f32x4){0.f,0.f,0.f,0.f}; s[0][1] = (f32x4){0.f,0.f,0.f,0.f};
        s[1][0] = (f32x4){0.f,0.f,0.f,0.f}; s[1][1] = (f32x4){0.f,0.f,0.f,0.f};
        for (int ck = 0; ck < 8; ck++) {
            f16x8 k0 = *(const f16x8*)(kb + (size_t)(j0      + col)*CC + ck*32 + grp*8);
            f16x8 k1 = *(const f16x8*)(kb + (size_t)(j0 + 16 + col)*CC + ck*32 + grp*8);
            s[0][0] = __builtin_amdgcn_mfma_f32_16x16x32_f16(qf[0][ck], k0, s[0][0], 0, 0, 0);
            s[0][1] = __builtin_amdgcn_mfma_f32_16x16x32_f16(qf[0][ck], k1, s[0][1], 0, 0, 0);
            s[1][0] = __builtin_amdgcn_mfma_f32_16x16x32_f16(qf[1][ck], k0, s[1][0], 0, 0, 0);
            s[1][1] = __builtin_amdgcn_mfma_f32_16x16x32_f16(qf[1][ck], k1, s[1][1], 0, 0, 0);
        }
        for (int t = 0; t < 2; t++) {
            float fs[4];
            for (int r = 0; r < 4; r++) {
                int idx = t*4 + r;
                float mx = fmaxf(s[t][0][r], s[t][1][r]);
                mx = fmaxf(mx, __shfl_xor(mx, 1));
                mx = fmaxf(mx, __shfl_xor(mx, 2));
                mx = fmaxf(mx, __shfl_xor(mx, 4));
                mx = fmaxf(mx, __shfl_xor(mx, 8));
                float mn = fmaxf(m[idx], mx);
                float f  = __expf(m[idx] - mn);
                m[idx] = mn;
                float p0 = __expf(s[t][0][r] - mn);
                float p1 = __expf(s[t][1][r] - mn);
                s[t][0][r] = p0; s[t][1][r] = p1;
                float ps = p0 + p1;
                ps += __shfl_xor(ps, 1);
                ps += __shfl_xor(ps, 2);
                ps += __shfl_xor(ps, 4);
                ps += __shfl_xor(ps, 8);
                l[idx] = l[idx] * f + ps;
                fs[r] = f;
            }
            for (int ck = 0; ck < 16; ck++) {
                O[t][ck][0] *= fs[0];
                O[t][ck][1] *= fs[1];
                O[t][ck][2] *= fs[2];
                O[t][ck][3] *= fs[3];
            }
            for (int r = 0; r < 4; r++) {
                plds[w][t][grp*4 + r][col]      = f2h_bits(s[t][0][r]);
                plds[w][t][grp*4 + r][16 + col] = f2h_bits(s[t][1][r]);
            }
        }
        // wave-local ordering: DS ops from one wave complete in order; fence the compiler
        asm volatile("s_waitcnt lgkmcnt(0)" ::: "memory");
        f16x8 pf0 = *(const f16x8*)&plds[w][0][col][grp*8];
        f16x8 pf1 = *(const f16x8*)&plds[w][1][col][grp*8];
        for (int ck = 0; ck < 16; ck++) {
            f16x8 vf = *(const f16x8*)(vb + (size_t)(ck*16 + col)*NN + j0 + grp*8);
            O[0][ck] = __builtin_amdgcn_mfma_f32_16x16x32_f16(pf0, vf, O[0][ck], 0, 0, 0);
            O[1][ck] = __builtin_amdgcn_mfma_f32_16x16x32_f16(pf1, vf, O[1][ck], 0, 0, 0);
        }
    }

    // normalized per-wave partial -> LDS
    for (int t = 0; t < 2; t++) {
        float inv[4];
        for (int r = 0; r < 4; r++) inv[r] = 1.f / l[t*4 + r];
        for (int ck = 0; ck < 16; ck++)
            for (int r = 0; r < 4; r++)
                SM[w][t*16 + grp*4 + r][ck*16 + col] = f2h_bits(O[t][ck][r] * inv[r]);
    }
    if (col == 0)
        for (int t = 0; t < 2; t++)
            for (int r = 0; r < 4; r++)
                MLs[w][t*16 + grp*4 + r] = make_float2(m[t*4+r], l[t*4+r]);
    __syncthreads();

    // merge 8 per-wave partials; 16 threads per query row, 16 channels each
    int q  = tid >> 4;
    int c0 = (tid & 15) * 16;
    float M = -1e30f;
    for (int i = 0; i < NWAVE; i++) M = fmaxf(M, MLs[i][q].x);
    float wt[NWAVE]; float L = 0.f;
    for (int i = 0; i < NWAVE; i++) {
        wt[i] = MLs[i][q].y * __expf(MLs[i][q].x - M);
        L += wt[i];
    }
    float invL = 1.f / L;
    for (int i = 0; i < NWAVE; i++) wt[i] *= invL;
    float acc[16];
    for (int e = 0; e < 16; e++) acc[e] = 0.f;
    for (int i = 0; i < NWAVE; i++) {
        f16x8 a0 = *(const f16x8*)&SM[i][q][c0];
        f16x8 a1 = *(const f16x8*)&SM[i][q][c0 + 8];
        for (int e = 0; e < 8; e++) {
            acc[e]     += wt[i] * (float)a0[e];
            acc[e + 8] += wt[i] * (float)a1[e];
        }
    }
    union { _Float16 h[8]; uint4 u; } o0, o1;
    for (int e = 0; e < 8; e++) { o0.h[e] = (_Float16)acc[e]; o1.h[e] = (_Float16)acc[e+8]; }
    unsigned short* dst = aT + (size_t)b*NN*CC + (size_t)(i0 + q)*CC + c0;
    *(uint4*)dst = o0.u;
    *(uint4*)(dst + 8) = o1.u;
}

// ------------- Kernel 6: output projection + bias + residual (fp16 weights, fp32 out) -------------
__global__ __launch_bounds__(256) void proj_out_kernel(
    const unsigned short* __restrict__ aT,
    const unsigned short* __restrict__ wp16, const float* __restrict__ bp,
    const float* __restrict__ x, float* __restrict__ out)
{
    int b = blockIdx.z;
    int i0 = blockIdx.x * 64, o0 = blockIdx.y * 64;
    int lane = threadIdx.x & 63, wid = threadIdx.x >> 6;
    int col = lane & 15, grp = lane >> 4;
    int ibase = i0 + wid * 16;
    const unsigned short* ab = aT + (size_t)b*NN*CC;
    f32x4 acc[4];
    for (int ot = 0; ot < 4; ot++) acc[ot] = (f32x4){0.f,0.f,0.f,0.f};
    for (int ck = 0; ck < 8; ck++) {
        f16x8 af = *(const f16x8*)(ab + (size_t)(ibase + col)*CC + ck*32 + grp*8);
        for (int ot = 0; ot < 4; ot++) {
            f16x8 bf = *(const f16x8*)(wp16 + (size_t)(o0 + ot*16 + col)*CC + ck*32 + grp*8);
            acc[ot] = __builtin_amdgcn_mfma_f32_16x16x32_f16(af, bf, acc[ot], 0, 0, 0);
        }
    }
    int iw = ibase + grp * 4;
    for (int ot = 0; ot < 4; ot++) {
        int o = o0 + ot*16 + col;
        float bo = bp[o];
        size_t base = (size_t)b*CC*NN + (size_t)o*NN + iw;
        float4 x4 = *(const float4*)(x + base);
        float4 r;
        r.x = x4.x + acc[ot][0] + bo;
        r.y = x4.y + acc[ot][1] + bo;
        r.z = x4.z + acc[ot][2] + bo;
        r.w = x4.w + acc[ot][3] + bo;
        *(float4*)(out + base) = r;
    }
}

extern "C" void kernel_launch(void* const* d_in, const int* in_sizes, int n_in,
                              void* d_out, int out_size, void* d_ws, size_t ws_size,
                              hipStream_t stream) {
    const float* x  = (const float*)d_in[0];
    const float* gs = (const float*)d_in[1];
    const float* gb = (const float*)d_in[2];
    const float* wq = (const float*)d_in[3];
    const float* bq = (const float*)d_in[4];
    const float* wk = (const float*)d_in[5];
    const float* bk = (const float*)d_in[6];
    const float* wv = (const float*)d_in[7];
    const float* bv = (const float*)d_in[8];
    const float* wp = (const float*)d_in[9];
    const float* bp = (const float*)d_in[10];
    float* out = (float*)d_out;

    char* ws = (char*)d_ws;
    const size_t sz = (size_t)BB * NN * CC * sizeof(unsigned short);  // 4 MB
    unsigned short* hT  = (unsigned short*)(ws);
    unsigned short* qT  = (unsigned short*)(ws + sz);
    unsigned short* kT  = (unsigned short*)(ws + 2*sz);
    unsigned short* vC  = (unsigned short*)(ws + 3*sz);
    unsigned short* aT  = (unsigned short*)(ws + 4*sz);
    unsigned short* w16 = (unsigned short*)(ws + 5*sz);          // 4 slabs x 128 KB
    float* stats        = (float*)(ws + 5*sz + 4*CC*CC*sizeof(unsigned short));

    prep_w16_kernel<<<dim3(CC*CC/4/256, 4), 256, 0, stream>>>(wq, wk, wv, wp, w16);
    gn_stats_kernel<<<dim3(GG, BB), 256, 0, stream>>>(x, stats);
    gn_apply_kernel<<<dim3(NN/64, BB), 256, 0, stream>>>(x, gs, gb, stats, hT);
    proj_qk_kernel<<<dim3(NN/64, CC/64, 2*BB), 256, 0, stream>>>(hT, w16, bq, bk, qT, kT);
    proj_v_kernel<<<dim3(NN/64, CC/64, BB), 256, 0, stream>>>(hT, w16 + 2*CC*CC, bv, vC);
    attn_kernel<<<dim3(NN/QB, BB), NWAVE*64, 0, stream>>>(qT, kT, vC, aT);
    proj_out_kernel<<<dim3(NN/64, CC/64, BB), 256, 0, stream>>>(aT, w16 + 3*CC*CC, bp, x, out);
}

// Round 3
// 146.823 us; speedup vs baseline: 2.5883x; 1.6011x over previous
//
#include <hip/hip_runtime.h>
#include <hip/hip_bf16.h>
#include <math.h>

#define BB 2
#define CC 256
#define GG 32
#define NN 4096
#define EPSF 1e-6f
#define JSPLIT 8
#define JBLK (NN / JSPLIT)   // 512 j per block
#define CH 32                // j chunk
#define NT (JBLK / CH)       // 16 chunks
#define QTILE 64             // queries per attn block (4 waves x 16)
#define LOG2E 1.4426950408889634f

typedef _Float16 f16x8 __attribute__((ext_vector_type(8)));
typedef float f32x4 __attribute__((ext_vector_type(4)));

static __device__ __forceinline__ unsigned short f2h_bits(float f) {
    _Float16 h = (_Float16)f;
    return __builtin_bit_cast(unsigned short, h);
}
static __device__ __forceinline__ unsigned pkh2(float a, float b) {
    return __builtin_bit_cast(unsigned, __builtin_amdgcn_cvt_pkrtz(a, b));
}
static __device__ __forceinline__ void gload16(const void* g, void* l) {
    __builtin_amdgcn_global_load_lds(
        (const __attribute__((address_space(1))) void*)g,
        (__attribute__((address_space(3))) void*)l, 16, 0, 0);
}

// ---------------- Kernel 0: weights -> fp16 (wq pre-scaled by c^-0.5 * log2e) ----------------
__global__ __launch_bounds__(256) void prep_w16_kernel(
    const float* __restrict__ wq, const float* __restrict__ wk,
    const float* __restrict__ wv, const float* __restrict__ wp,
    unsigned short* __restrict__ w16)
{
    int m = blockIdx.y;
    const float* src = (m == 0) ? wq : (m == 1) ? wk : (m == 2) ? wv : wp;
    float scale = (m == 0) ? 0.0625f * LOG2E : 1.0f;
    int idx = blockIdx.x * 256 + threadIdx.x;   // unit = 4 floats
    float4 v = ((const float4*)src)[idx];
    union { _Float16 h[4]; uint2 u; } pk;
    pk.h[0] = (_Float16)(v.x * scale);
    pk.h[1] = (_Float16)(v.y * scale);
    pk.h[2] = (_Float16)(v.z * scale);
    pk.h[3] = (_Float16)(v.w * scale);
    *(uint2*)(w16 + (size_t)m * CC * CC + (size_t)idx * 4) = pk.u;
}

// ---------------- Kernel 1: GroupNorm partial sums (4 parts per (b,g)) ----------------
__global__ __launch_bounds__(256) void gn_part_kernel(
    const float* __restrict__ x, float2* __restrict__ part)
{
    int g = blockIdx.x, p = blockIdx.y, b = blockIdx.z;
    const float* base = x + ((size_t)b * CC + (size_t)g * 8) * NN + (size_t)p * 8192;
    int t = threadIdx.x;
    float s = 0.f, ss = 0.f;
    for (int idx = t; idx < 2048; idx += 256) {
        float4 v4 = ((const float4*)base)[idx];
        s  += v4.x + v4.y + v4.z + v4.w;
        ss += v4.x*v4.x + v4.y*v4.y + v4.z*v4.z + v4.w*v4.w;
    }
    for (int off = 32; off; off >>= 1) {
        s  += __shfl_down(s,  off);
        ss += __shfl_down(ss, off);
    }
    __shared__ float red[8];
    int wid = t >> 6;
    if ((t & 63) == 0) { red[wid*2] = s; red[wid*2+1] = ss; }
    __syncthreads();
    if (t == 0) {
        part[(b*GG + g)*4 + p] = make_float2(red[0]+red[2]+red[4]+red[6],
                                             red[1]+red[3]+red[5]+red[7]);
    }
}

// ------------- Kernel 2: apply GN (finalize stats inline), write h_T (b,n,c) fp16 -------------
__global__ __launch_bounds__(256) void gn_apply_kernel(
    const float* __restrict__ x, const float* __restrict__ sc,
    const float* __restrict__ bi, const float2* __restrict__ part,
    unsigned short* __restrict__ hT)
{
    int b  = blockIdx.y;
    int i0 = blockIdx.x * 64;
    int t  = threadIdx.x;
    __shared__ unsigned short tile[64][264];
    __shared__ float s_mean[GG], s_rstd[GG], s_sc[CC], s_bi[CC];
    if (t < GG) {
        float2 p0 = part[(b*GG + t)*4 + 0];
        float2 p1 = part[(b*GG + t)*4 + 1];
        float2 p2 = part[(b*GG + t)*4 + 2];
        float2 p3 = part[(b*GG + t)*4 + 3];
        float S  = p0.x + p1.x + p2.x + p3.x;
        float SS = p0.y + p1.y + p2.y + p3.y;
        float mean = S / 32768.f;
        float var  = SS / 32768.f - mean * mean;
        s_mean[t] = mean;
        s_rstd[t] = rsqrtf(var + EPSF);
    }
    s_sc[t] = sc[t];
    s_bi[t] = bi[t];
    __syncthreads();
    int i4 = (t & 15) * 4;
    int cb = t >> 4;
    for (int k = 0; k < 16; k++) {
        int c = cb + k * 16;
        float4 v4 = *(const float4*)(x + ((size_t)b*CC + c)*NN + i0 + i4);
        float a = s_rstd[c >> 3] * s_sc[c];
        float d = s_bi[c] - s_mean[c >> 3] * a;
        tile[i4+0][c] = f2h_bits(v4.x * a + d);
        tile[i4+1][c] = f2h_bits(v4.y * a + d);
        tile[i4+2][c] = f2h_bits(v4.z * a + d);
        tile[i4+3][c] = f2h_bits(v4.w * a + d);
    }
    __syncthreads();
    int row = t >> 2, c0 = (t & 3) * 64;
    unsigned short* dst = hT + (size_t)b*NN*CC + (size_t)(i0 + row)*CC + c0;
    for (int k = 0; k < 8; k++) {
        uint4 u = *(const uint4*)&tile[row][c0 + k*8];
        *(uint4*)(dst + k*8) = u;
    }
}

// ------------- Kernel 3: q,k projections (fp16 weights) -------------
__global__ __launch_bounds__(256) void proj_qk_kernel(
    const unsigned short* __restrict__ hT,
    const unsigned short* __restrict__ w16,
    const float* __restrict__ bq, const float* __restrict__ bk,
    unsigned short* __restrict__ qT, unsigned short* __restrict__ kT)
{
    int b = blockIdx.z >> 1, p = blockIdx.z & 1;
    const unsigned short* wgt = w16 + (size_t)p * CC * CC;
    const float* bias = p ? bk : bq;
    unsigned short* out = p ? kT : qT;
    float oscale = p ? 1.0f : 0.0625f * LOG2E;   // bias scale; weights pre-scaled
    int i0 = blockIdx.x * 64, o0 = blockIdx.y * 64;
    int lane = threadIdx.x & 63, wid = threadIdx.x >> 6;
    int col = lane & 15, grp = lane >> 4;
    int ow = o0 + wid * 16;
    const unsigned short* hb = hT + (size_t)b*NN*CC;
    f32x4 acc[4];
    for (int it = 0; it < 4; it++) acc[it] = (f32x4){0.f,0.f,0.f,0.f};
    for (int ck = 0; ck < 8; ck++) {
        f16x8 af = *(const f16x8*)(wgt + (size_t)(ow + col)*CC + ck*32 + grp*8);
        for (int it = 0; it < 4; it++) {
            f16x8 bf = *(const f16x8*)(hb + (size_t)(i0 + it*16 + col)*CC + ck*32 + grp*8);
            acc[it] = __builtin_amdgcn_mfma_f32_16x16x32_f16(af, bf, acc[it], 0, 0, 0);
        }
    }
    int obase = ow + grp * 4;
    float b0 = bias[obase]*oscale, b1 = bias[obase+1]*oscale,
          b2 = bias[obase+2]*oscale, b3 = bias[obase+3]*oscale;
    for (int it = 0; it < 4; it++) {
        int i = i0 + it*16 + col;
        union { _Float16 h[4]; uint2 u; } pk;
        pk.h[0] = (_Float16)(acc[it][0] + b0);
        pk.h[1] = (_Float16)(acc[it][1] + b1);
        pk.h[2] = (_Float16)(acc[it][2] + b2);
        pk.h[3] = (_Float16)(acc[it][3] + b3);
        *(uint2*)(out + (size_t)b*NN*CC + (size_t)i*CC + obase) = pk.u;
    }
}

// ------------- Kernel 4: v projection: v (b, c, n) fp16 -------------
__global__ __launch_bounds__(256) void proj_v_kernel(
    const unsigned short* __restrict__ hT,
    const unsigned short* __restrict__ wv16, const float* __restrict__ bv,
    unsigned short* __restrict__ vC)
{
    int b = blockIdx.z;
    int i0 = blockIdx.x * 64, o0 = blockIdx.y * 64;
    int lane = threadIdx.x & 63, wid = threadIdx.x >> 6;
    int col = lane & 15, grp = lane >> 4;
    int ibase = i0 + wid * 16;
    const unsigned short* hb = hT + (size_t)b*NN*CC;
    f32x4 acc[4];
    for (int ot = 0; ot < 4; ot++) acc[ot] = (f32x4){0.f,0.f,0.f,0.f};
    for (int ck = 0; ck < 8; ck++) {
        f16x8 af = *(const f16x8*)(hb + (size_t)(ibase + col)*CC + ck*32 + grp*8);
        for (int ot = 0; ot < 4; ot++) {
            f16x8 bf = *(const f16x8*)(wv16 + (size_t)(o0 + ot*16 + col)*CC + ck*32 + grp*8);
            acc[ot] = __builtin_amdgcn_mfma_f32_16x16x32_f16(af, bf, acc[ot], 0, 0, 0);
        }
    }
    int iw = ibase + grp * 4;
    for (int ot = 0; ot < 4; ot++) {
        int o = o0 + ot*16 + col;
        float bo = bv[o];
        union { _Float16 h[4]; uint2 u; } pk;
        pk.h[0] = (_Float16)(acc[ot][0] + bo);
        pk.h[1] = (_Float16)(acc[ot][1] + bo);
        pk.h[2] = (_Float16)(acc[ot][2] + bo);
        pk.h[3] = (_Float16)(acc[ot][3] + bo);
        *(uint2*)(vC + (size_t)b*CC*NN + (size_t)o*NN + iw) = pk.u;
    }
}

// ------------- Kernel 5: flash attention, cooperative LDS staging + j-split partials -------------
// Block: 4 waves x 16q = 64 queries, j-range = 512 (JSPLIT=8 blocks per q-tile).
// K tile [32j][256c] in LDS, rows 512B, XOR-swizzled 16B blocks: cb' = cb ^ (j&7).
// V tile [256c][32j] in LDS, rows 64B,  XOR-swizzled 16B blocks: cb' = cb ^ ((c>>1)&3).
// QK^T swapped (mfma(K,Q)) -> per-lane q = lane&15; P repack via 8 in-reg shuffles.
__global__ __launch_bounds__(256, 3) void attn_kernel(
    const unsigned short* __restrict__ qT,
    const unsigned short* __restrict__ kT,
    const unsigned short* __restrict__ vC,
    unsigned short* __restrict__ pO,
    float2* __restrict__ ml)
{
    int qt = blockIdx.x, s = blockIdx.y, b = blockIdx.z;
    int tid = threadIdx.x, w = tid >> 6, lane = tid & 63;
    int l15 = lane & 15, grp = lane >> 4;
    int q0 = qt * QTILE + w * 16;
    int jlo = s * JBLK;

    __shared__ unsigned short bufK[8192];   // 16 KB
    __shared__ unsigned short bufV[8192];   // 16 KB

    const unsigned short* qb = qT + (size_t)b * NN * CC;
    const unsigned short* kb = kT + (size_t)b * NN * CC;
    const unsigned short* vb = vC + (size_t)b * CC * NN;

    f16x8 qf[8];
    #pragma unroll
    for (int ck = 0; ck < 8; ck++)
        qf[ck] = *(const f16x8*)(qb + (size_t)(q0 + l15)*CC + ck*32 + grp*8);

    // staging constants: this wave issues K/V 1KB-chunks {4w..4w+3}
    int koff[4], voff[4];
    #pragma unroll
    for (int e = 0; e < 4; e++) {
        int blk = (4*w + e)*64 + lane;
        int kj = blk >> 5, kcb = blk & 31;
        koff[e] = kj*CC + ((kcb ^ (kj & 7)) * 8);
        int vc = blk >> 2, vcb = blk & 3;
        voff[e] = vc*NN + ((vcb ^ ((vc >> 1) & 3)) * 8);
    }
    // LDS read constants
    int kru = l15 * 512;                 // K row base (bytes), jt=0
    int krw = (l15 & 7) << 4;            // K row XOR term
    int g16 = grp << 4;
    int vrb = l15*64 + ((grp ^ ((l15 >> 1) & 3)) << 4);   // V read base (bytes)

    f32x4 O[16];
    #pragma unroll
    for (int ck = 0; ck < 16; ck++) O[ck] = (f32x4){0.f,0.f,0.f,0.f};
    float m = -1e30f, l = 0.f;

    const char* kbase = (const char*)bufK;
    const char* vbase = (const char*)bufV;

    for (int t = 0; t < NT; t++) {
        int j0n = jlo + t * CH;
        #pragma unroll
        for (int e = 0; e < 4; e++) {
            gload16(kb + (size_t)j0n*CC + koff[e], bufK + (4*w + e)*512);
            gload16(vb + voff[e] + j0n,            bufV + (4*w + e)*512);
        }
        __syncthreads();   // compiler drains vmcnt before s_barrier

        // QK^T swapped: s0 = j rows 0..15, s1 = j rows 16..31; D col = q
        f32x4 s0 = (f32x4){0.f,0.f,0.f,0.f}, s1 = (f32x4){0.f,0.f,0.f,0.f};
        #pragma unroll
        for (int ck = 0; ck < 8; ck++) {
            int cx = ((ck*64) | g16) ^ krw;
            f16x8 k0 = *(const f16x8*)(kbase + kru + cx);
            f16x8 k1 = *(const f16x8*)(kbase + 8192 + kru + cx);
            s0 = __builtin_amdgcn_mfma_f32_16x16x32_f16(k0, qf[ck], s0, 0, 0, 0);
            s1 = __builtin_amdgcn_mfma_f32_16x16x32_f16(k1, qf[ck], s1, 0, 0, 0);
        }
        // online softmax in exp2 domain; per-lane q = l15
        float x0 = fmaxf(fmaxf(s0[0], s0[1]), fmaxf(s0[2], s0[3]));
        float x1 = fmaxf(fmaxf(s1[0], s1[1]), fmaxf(s1[2], s1[3]));
        float mx = fmaxf(x0, x1);
        mx = fmaxf(mx, __shfl_xor(mx, 16));
        mx = fmaxf(mx, __shfl_xor(mx, 32));
        float f = 1.f;
        bool up = !__all(mx <= m);
        if (up) {
            float mn = fmaxf(m, mx);
            f = exp2f(m - mn);
            m = mn;
        }
        s0[0] = exp2f(s0[0] - m); s0[1] = exp2f(s0[1] - m);
        s0[2] = exp2f(s0[2] - m); s0[3] = exp2f(s0[3] - m);
        s1[0] = exp2f(s1[0] - m); s1[1] = exp2f(s1[1] - m);
        s1[2] = exp2f(s1[2] - m); s1[3] = exp2f(s1[3] - m);
        float ps = ((s0[0]+s0[1]) + (s0[2]+s0[3])) + ((s1[0]+s1[1]) + (s1[2]+s1[3]));
        ps += __shfl_xor(ps, 16);
        ps += __shfl_xor(ps, 32);
        l = l * f + ps;
        if (up) {
            int fb = (lane & 48) | (grp << 2);
            float fs0 = __shfl(f, fb),   fs1 = __shfl(f, fb+1);
            float fs2 = __shfl(f, fb+2), fs3 = __shfl(f, fb+3);
            f32x4 fv = (f32x4){fs0, fs1, fs2, fs3};
            #pragma unroll
            for (int ck = 0; ck < 16; ck++) O[ck] *= fv;
        }
        // pack P to fp16 and exchange into PV A-fragment layout
        unsigned pk0 = pkh2(s0[0], s0[1]);
        unsigned pk1 = pkh2(s0[2], s0[3]);
        unsigned pk2 = pkh2(s1[0], s1[1]);
        unsigned pk3 = pkh2(s1[2], s1[3]);
        int srcA = (((grp << 1)    ) & 3) * 16 + l15;
        int srcB = (((grp << 1) + 1) & 3) * 16 + l15;
        bool lo = (grp < 2);
        unsigned u0A = __shfl(pk0, srcA), u2A = __shfl(pk2, srcA);
        unsigned u1A = __shfl(pk1, srcA), u3A = __shfl(pk3, srcA);
        unsigned u0B = __shfl(pk0, srcB), u2B = __shfl(pk2, srcB);
        unsigned u1B = __shfl(pk1, srcB), u3B = __shfl(pk3, srcB);
        uint4 pu;
        pu.x = lo ? u0A : u2A;
        pu.y = lo ? u1A : u3A;
        pu.z = lo ? u0B : u2B;
        pu.w = lo ? u1B : u3B;
        f16x8 pf = __builtin_bit_cast(f16x8, pu);
        // PV
        #pragma unroll
        for (int ck = 0; ck < 16; ck++) {
            f16x8 vf = *(const f16x8*)(vbase + ck*1024 + vrb);
            O[ck] = __builtin_amdgcn_mfma_f32_16x16x32_f16(pf, vf, O[ck], 0, 0, 0);
        }
        __syncthreads();   // all waves done reading before next stage
    }

    // epilogue: normalized partial + (m,l)
    float invl = 1.f / l;
    int ib = (lane & 48) | (grp << 2);
    float iv0 = __shfl(invl, ib),   iv1 = __shfl(invl, ib+1);
    float iv2 = __shfl(invl, ib+2), iv3 = __shfl(invl, ib+3);
    unsigned short* po = pO + ((size_t)(s*BB + b)*NN + q0) * CC;
    #pragma unroll
    for (int ck = 0; ck < 16; ck++) {
        po[(size_t)(grp*4+0)*CC + ck*16 + l15] = f2h_bits(O[ck][0] * iv0);
        po[(size_t)(grp*4+1)*CC + ck*16 + l15] = f2h_bits(O[ck][1] * iv1);
        po[(size_t)(grp*4+2)*CC + ck*16 + l15] = f2h_bits(O[ck][2] * iv2);
        po[(size_t)(grp*4+3)*CC + ck*16 + l15] = f2h_bits(O[ck][3] * iv3);
    }
    if (lane < 16)
        ml[(size_t)(s*BB + b)*NN + q0 + lane] = make_float2(m, l);
}

// ------------- Kernel 5b: merge JSPLIT partials -------------
__global__ __launch_bounds__(256) void attn_merge_kernel(
    const unsigned short* __restrict__ pO, const float2* __restrict__ ml,
    unsigned short* __restrict__ aT)
{
    int t = threadIdx.x;
    int qrow = blockIdx.x * 16 + (t >> 4);   // b*NN + q
    int c0 = (t & 15) * 16;
    float M = -1e30f;
    float m8[JSPLIT], l8[JSPLIT];
    #pragma unroll
    for (int s = 0; s < JSPLIT; s++) {
        float2 v = ml[(size_t)s*BB*NN + qrow];
        m8[s] = v.x; l8[s] = v.y;
        M = fmaxf(M, v.x);
    }
    float W = 0.f, wt[JSPLIT];
    #pragma unroll
    for (int s = 0; s < JSPLIT; s++) { wt[s] = l8[s] * exp2f(m8[s] - M); W += wt[s]; }
    float iW = 1.f / W;
    float acc[16];
    #pragma unroll
    for (int e = 0; e < 16; e++) acc[e] = 0.f;
    #pragma unroll
    for (int s = 0; s < JSPLIT; s++) {
        const unsigned short* p = pO + ((size_t)s*BB*NN + qrow)*CC + c0;
        f16x8 a0 = *(const f16x8*)p;
        f16x8 a1 = *(const f16x8*)(p + 8);
        float ws = wt[s] * iW;
        #pragma unroll
        for (int e = 0; e < 8; e++) {
            acc[e]     += ws * (float)a0[e];
            acc[e + 8] += ws * (float)a1[e];
        }
    }
    union { _Float16 h[8]; uint4 u; } o0, o1;
    #pragma unroll
    for (int e = 0; e < 8; e++) { o0.h[e] = (_Float16)acc[e]; o1.h[e] = (_Float16)acc[e+8]; }
    unsigned short* dst = aT + (size_t)qrow*CC + c0;
    *(uint4*)dst = o0.u;
    *(uint4*)(dst + 8) = o1.u;
}

// ------------- Kernel 6: output projection + bias + residual (fp32 out) -------------
__global__ __launch_bounds__(256) void proj_out_kernel(
    const unsigned short* __restrict__ aT,
    const unsigned short* __restrict__ wp16, const float* __restrict__ bp,
    const float* __restrict__ x, float* __restrict__ out)
{
    int b = blockIdx.z;
    int i0 = blockIdx.x * 64, o0 = blockIdx.y * 64;
    int lane = threadIdx.x & 63, wid = threadIdx.x >> 6;
    int col = lane & 15, grp = lane >> 4;
    int ibase = i0 + wid * 16;
    const unsigned short* ab = aT + (size_t)b*NN*CC;
    f32x4 acc[4];
    for (int ot = 0; ot < 4; ot++) acc[ot] = (f32x4){0.f,0.f,0.f,0.f};
    for (int ck = 0; ck < 8; ck++) {
        f16x8 af = *(const f16x8*)(ab + (size_t)(ibase + col)*CC + ck*32 + grp*8);
        for (int ot = 0; ot < 4; ot++) {
            f16x8 bf = *(const f16x8*)(wp16 + (size_t)(o0 + ot*16 + col)*CC + ck*32 + grp*8);
            acc[ot] = __builtin_amdgcn_mfma_f32_16x16x32_f16(af, bf, acc[ot], 0, 0, 0);
        }
    }
    int iw = ibase + grp * 4;
    for (int ot = 0; ot < 4; ot++) {
        int o = o0 + ot*16 + col;
        float bo = bp[o];
        size_t base = (size_t)b*CC*NN + (size_t)o*NN + iw;
        float4 x4 = *(const float4*)(x + base);
        float4 r;
        r.x = x4.x + acc[ot][0] + bo;
        r.y = x4.y + acc[ot][1] + bo;
        r.z = x4.z + acc[ot][2] + bo;
        r.w = x4.w + acc[ot][3] + bo;
        *(float4*)(out + base) = r;
    }
}

extern "C" void kernel_launch(void* const* d_in, const int* in_sizes, int n_in,
                              void* d_out, int out_size, void* d_ws, size_t ws_size,
                              hipStream_t stream) {
    const float* x  = (const float*)d_in[0];
    const float* gs = (const float*)d_in[1];
    const float* gb = (const float*)d_in[2];
    const float* wq = (const float*)d_in[3];
    const float* bq = (const float*)d_in[4];
    const float* wk = (const float*)d_in[5];
    const float* bk = (const float*)d_in[6];
    const float* wv = (const float*)d_in[7];
    const float* bv = (const float*)d_in[8];
    const float* wp = (const float*)d_in[9];
    const float* bp = (const float*)d_in[10];
    float* out = (float*)d_out;

    char* ws = (char*)d_ws;
    const size_t sz = (size_t)BB * NN * CC * sizeof(unsigned short);   // 4 MB
    unsigned short* hT  = (unsigned short*)(ws);
    unsigned short* qT  = (unsigned short*)(ws + sz);
    unsigned short* kT  = (unsigned short*)(ws + 2*sz);
    unsigned short* vC  = (unsigned short*)(ws + 3*sz);
    unsigned short* aT  = (unsigned short*)(ws + 4*sz);
    unsigned short* w16 = (unsigned short*)(ws + 5*sz);                 // 512 KB
    float2* part        = (float2*)(ws + 5*sz + 512*1024);              // 2 KB
    float2* ml          = (float2*)(ws + 5*sz + 768*1024);              // 512 KB
    unsigned short* pO  = (unsigned short*)(ws + 5*sz + 1280*1024);     // 32 MB

    prep_w16_kernel<<<dim3(CC*CC/4/256, 4), 256, 0, stream>>>(wq, wk, wv, wp, w16);
    gn_part_kernel<<<dim3(GG, 4, BB), 256, 0, stream>>>(x, part);
    gn_apply_kernel<<<dim3(NN/64, BB), 256, 0, stream>>>(x, gs, gb, part, hT);
    proj_qk_kernel<<<dim3(NN/64, CC/64, 2*BB), 256, 0, stream>>>(hT, w16, bq, bk, qT, kT);
    proj_v_kernel<<<dim3(NN/64, CC/64, BB), 256, 0, stream>>>(hT, w16 + 2*CC*CC, bv, vC);
    attn_kernel<<<dim3(NN/QTILE, JSPLIT, BB), 256, 0, stream>>>(qT, kT, vC, pO, ml);
    attn_merge_kernel<<<dim3(BB*NN/16), 256, 0, stream>>>(pO, ml, aT);
    proj_out_kernel<<<dim3(NN/64, CC/64, BB), 256, 0, stream>>>(aT, w16 + 3*CC*CC, bp, x, out);
}

// Round 4
// 141.892 us; speedup vs baseline: 2.6782x; 1.0348x over previous
//
#include <hip/hip_runtime.h>
#include <hip/hip_bf16.h>
#include <math.h>

#define BB 2
#define CC 256
#define GG 32
#define NN 4096
#define EPSF 1e-6f
#define JSPLIT 8
#define JBLK (NN / JSPLIT)   // 512 j per block
#define CH 32                // j chunk
#define NT (JBLK / CH)       // 16 chunks
#define QTILE 128            // queries per attn block (4 waves x 32)
#define LOG2E 1.4426950408889634f

typedef _Float16 f16x8 __attribute__((ext_vector_type(8)));
typedef float f32x4 __attribute__((ext_vector_type(4)));

static __device__ __forceinline__ unsigned short f2h_bits(float f) {
    _Float16 h = (_Float16)f;
    return __builtin_bit_cast(unsigned short, h);
}
static __device__ __forceinline__ unsigned pkh2(float a, float b) {
    return __builtin_bit_cast(unsigned, __builtin_amdgcn_cvt_pkrtz(a, b));
}
static __device__ __forceinline__ void gload16(const void* g, void* l) {
    __builtin_amdgcn_global_load_lds(
        (const __attribute__((address_space(1))) void*)g,
        (__attribute__((address_space(3))) void*)l, 16, 0, 0);
}

// ---------------- Kernel 0: weights -> fp16 (wq pre-scaled by c^-0.5 * log2e) ----------------
__global__ __launch_bounds__(256) void prep_w16_kernel(
    const float* __restrict__ wq, const float* __restrict__ wk,
    const float* __restrict__ wv, const float* __restrict__ wp,
    unsigned short* __restrict__ w16)
{
    int m = blockIdx.y;
    const float* src = (m == 0) ? wq : (m == 1) ? wk : (m == 2) ? wv : wp;
    float scale = (m == 0) ? 0.0625f * LOG2E : 1.0f;
    int idx = blockIdx.x * 256 + threadIdx.x;   // unit = 4 floats
    float4 v = ((const float4*)src)[idx];
    union { _Float16 h[4]; uint2 u; } pk;
    pk.h[0] = (_Float16)(v.x * scale);
    pk.h[1] = (_Float16)(v.y * scale);
    pk.h[2] = (_Float16)(v.z * scale);
    pk.h[3] = (_Float16)(v.w * scale);
    *(uint2*)(w16 + (size_t)m * CC * CC + (size_t)idx * 4) = pk.u;
}

// ---------------- Kernel 1: GroupNorm partial sums (4 parts per (b,g)) ----------------
__global__ __launch_bounds__(256) void gn_part_kernel(
    const float* __restrict__ x, float2* __restrict__ part)
{
    int g = blockIdx.x, p = blockIdx.y, b = blockIdx.z;
    const float* base = x + ((size_t)b * CC + (size_t)g * 8) * NN + (size_t)p * 8192;
    int t = threadIdx.x;
    float s = 0.f, ss = 0.f;
    for (int idx = t; idx < 2048; idx += 256) {
        float4 v4 = ((const float4*)base)[idx];
        s  += v4.x + v4.y + v4.z + v4.w;
        ss += v4.x*v4.x + v4.y*v4.y + v4.z*v4.z + v4.w*v4.w;
    }
    for (int off = 32; off; off >>= 1) {
        s  += __shfl_down(s,  off);
        ss += __shfl_down(ss, off);
    }
    __shared__ float red[8];
    int wid = t >> 6;
    if ((t & 63) == 0) { red[wid*2] = s; red[wid*2+1] = ss; }
    __syncthreads();
    if (t == 0) {
        part[(b*GG + g)*4 + p] = make_float2(red[0]+red[2]+red[4]+red[6],
                                             red[1]+red[3]+red[5]+red[7]);
    }
}

// ------------- Kernel 2: apply GN (finalize stats inline), write h_T (b,n,c) fp16 -------------
__global__ __launch_bounds__(256) void gn_apply_kernel(
    const float* __restrict__ x, const float* __restrict__ sc,
    const float* __restrict__ bi, const float2* __restrict__ part,
    unsigned short* __restrict__ hT)
{
    int b  = blockIdx.y;
    int i0 = blockIdx.x * 64;
    int t  = threadIdx.x;
    __shared__ unsigned short tile[64][264];
    __shared__ float s_mean[GG], s_rstd[GG], s_sc[CC], s_bi[CC];
    if (t < GG) {
        float2 p0 = part[(b*GG + t)*4 + 0];
        float2 p1 = part[(b*GG + t)*4 + 1];
        float2 p2 = part[(b*GG + t)*4 + 2];
        float2 p3 = part[(b*GG + t)*4 + 3];
        float S  = p0.x + p1.x + p2.x + p3.x;
        float SS = p0.y + p1.y + p2.y + p3.y;
        float mean = S / 32768.f;
        float var  = SS / 32768.f - mean * mean;
        s_mean[t] = mean;
        s_rstd[t] = rsqrtf(var + EPSF);
    }
    s_sc[t] = sc[t];
    s_bi[t] = bi[t];
    __syncthreads();
    int i4 = (t & 15) * 4;
    int cb = t >> 4;
    for (int k = 0; k < 16; k++) {
        int c = cb + k * 16;
        float4 v4 = *(const float4*)(x + ((size_t)b*CC + c)*NN + i0 + i4);
        float a = s_rstd[c >> 3] * s_sc[c];
        float d = s_bi[c] - s_mean[c >> 3] * a;
        tile[i4+0][c] = f2h_bits(v4.x * a + d);
        tile[i4+1][c] = f2h_bits(v4.y * a + d);
        tile[i4+2][c] = f2h_bits(v4.z * a + d);
        tile[i4+3][c] = f2h_bits(v4.w * a + d);
    }
    __syncthreads();
    int row = t >> 2, c0 = (t & 3) * 64;
    unsigned short* dst = hT + (size_t)b*NN*CC + (size_t)(i0 + row)*CC + c0;
    for (int k = 0; k < 8; k++) {
        uint4 u = *(const uint4*)&tile[row][c0 + k*8];
        *(uint4*)(dst + k*8) = u;
    }
}

// ------------- Kernel 3: q,k projections (fp16 weights) -------------
__global__ __launch_bounds__(256) void proj_qk_kernel(
    const unsigned short* __restrict__ hT,
    const unsigned short* __restrict__ w16,
    const float* __restrict__ bq, const float* __restrict__ bk,
    unsigned short* __restrict__ qT, unsigned short* __restrict__ kT)
{
    int b = blockIdx.z >> 1, p = blockIdx.z & 1;
    const unsigned short* wgt = w16 + (size_t)p * CC * CC;
    const float* bias = p ? bk : bq;
    unsigned short* out = p ? kT : qT;
    float oscale = p ? 1.0f : 0.0625f * LOG2E;   // bias scale; weights pre-scaled
    int i0 = blockIdx.x * 64, o0 = blockIdx.y * 64;
    int lane = threadIdx.x & 63, wid = threadIdx.x >> 6;
    int col = lane & 15, grp = lane >> 4;
    int ow = o0 + wid * 16;
    const unsigned short* hb = hT + (size_t)b*NN*CC;
    f32x4 acc[4];
    for (int it = 0; it < 4; it++) acc[it] = (f32x4){0.f,0.f,0.f,0.f};
    for (int ck = 0; ck < 8; ck++) {
        f16x8 af = *(const f16x8*)(wgt + (size_t)(ow + col)*CC + ck*32 + grp*8);
        for (int it = 0; it < 4; it++) {
            f16x8 bf = *(const f16x8*)(hb + (size_t)(i0 + it*16 + col)*CC + ck*32 + grp*8);
            acc[it] = __builtin_amdgcn_mfma_f32_16x16x32_f16(af, bf, acc[it], 0, 0, 0);
        }
    }
    int obase = ow + grp * 4;
    float b0 = bias[obase]*oscale, b1 = bias[obase+1]*oscale,
          b2 = bias[obase+2]*oscale, b3 = bias[obase+3]*oscale;
    for (int it = 0; it < 4; it++) {
        int i = i0 + it*16 + col;
        union { _Float16 h[4]; uint2 u; } pk;
        pk.h[0] = (_Float16)(acc[it][0] + b0);
        pk.h[1] = (_Float16)(acc[it][1] + b1);
        pk.h[2] = (_Float16)(acc[it][2] + b2);
        pk.h[3] = (_Float16)(acc[it][3] + b3);
        *(uint2*)(out + (size_t)b*NN*CC + (size_t)i*CC + obase) = pk.u;
    }
}

// ------------- Kernel 4: v projection: v (b, c, n) fp16 -------------
__global__ __launch_bounds__(256) void proj_v_kernel(
    const unsigned short* __restrict__ hT,
    const unsigned short* __restrict__ wv16, const float* __restrict__ bv,
    unsigned short* __restrict__ vC)
{
    int b = blockIdx.z;
    int i0 = blockIdx.x * 64, o0 = blockIdx.y * 64;
    int lane = threadIdx.x & 63, wid = threadIdx.x >> 6;
    int col = lane & 15, grp = lane >> 4;
    int ibase = i0 + wid * 16;
    const unsigned short* hb = hT + (size_t)b*NN*CC;
    f32x4 acc[4];
    for (int ot = 0; ot < 4; ot++) acc[ot] = (f32x4){0.f,0.f,0.f,0.f};
    for (int ck = 0; ck < 8; ck++) {
        f16x8 af = *(const f16x8*)(hb + (size_t)(ibase + col)*CC + ck*32 + grp*8);
        for (int ot = 0; ot < 4; ot++) {
            f16x8 bf = *(const f16x8*)(wv16 + (size_t)(o0 + ot*16 + col)*CC + ck*32 + grp*8);
            acc[ot] = __builtin_amdgcn_mfma_f32_16x16x32_f16(af, bf, acc[ot], 0, 0, 0);
        }
    }
    int iw = ibase + grp * 4;
    for (int ot = 0; ot < 4; ot++) {
        int o = o0 + ot*16 + col;
        float bo = bv[o];
        union { _Float16 h[4]; uint2 u; } pk;
        pk.h[0] = (_Float16)(acc[ot][0] + bo);
        pk.h[1] = (_Float16)(acc[ot][1] + bo);
        pk.h[2] = (_Float16)(acc[ot][2] + bo);
        pk.h[3] = (_Float16)(acc[ot][3] + bo);
        *(uint2*)(vC + (size_t)b*CC*NN + (size_t)o*NN + iw) = pk.u;
    }
}

// ------------- Kernel 5: flash attention, 32q/wave, double-buffered LDS staging -------------
// Block: 4 waves x 32q = 128 queries, j-range = 512 (JSPLIT=8 blocks per q-tile).
// K tile [32j][256c] in LDS, rows 512B, XOR-swizzled 16B blocks: cb' = cb ^ (j&7).
// V tile [256c][32j] in LDS, rows 64B,  XOR-swizzled 16B blocks: cb' = cb ^ ((c>>1)&3).
// QK^T swapped (mfma(K,Q)) -> per-lane q = lane&15; P repack via 8 in-reg shuffles per tile.
__global__ __launch_bounds__(256, 2) void attn_kernel(
    const unsigned short* __restrict__ qT,
    const unsigned short* __restrict__ kT,
    const unsigned short* __restrict__ vC,
    unsigned short* __restrict__ pO,
    float2* __restrict__ ml)
{
    int qt = blockIdx.x, s = blockIdx.y, b = blockIdx.z;
    int tid = threadIdx.x, w = tid >> 6, lane = tid & 63;
    int l15 = lane & 15, grp = lane >> 4;
    int q0 = qt * QTILE + w * 32;
    int jlo = s * JBLK;

    __shared__ unsigned short bufK[2][8192];   // 2 x 16 KB
    __shared__ unsigned short bufV[2][8192];   // 2 x 16 KB

    const unsigned short* qb = qT + (size_t)b * NN * CC;
    const unsigned short* kb = kT + (size_t)b * NN * CC;
    const unsigned short* vb = vC + (size_t)b * CC * NN;

    f16x8 qfA[8], qfB[8];
    #pragma unroll
    for (int ck = 0; ck < 8; ck++) {
        qfA[ck] = *(const f16x8*)(qb + (size_t)(q0 + l15)*CC + ck*32 + grp*8);
        qfB[ck] = *(const f16x8*)(qb + (size_t)(q0 + 16 + l15)*CC + ck*32 + grp*8);
    }

    // staging constants: this wave issues K/V 1KB-chunks {4w..4w+3}
    int koff[4], voff[4];
    #pragma unroll
    for (int e = 0; e < 4; e++) {
        int blk = (4*w + e)*64 + lane;
        int kj = blk >> 5, kcb = blk & 31;
        koff[e] = kj*CC + ((kcb ^ (kj & 7)) * 8);
        int vc = blk >> 2, vcb = blk & 3;
        voff[e] = vc*NN + ((vcb ^ ((vc >> 1) & 3)) * 8);
    }
    // LDS read constants
    int kru = l15 * 512;                 // K row base (bytes), jt=0
    int krw = (l15 & 7) << 4;            // K row XOR term
    int g16 = grp << 4;
    int vrb = l15*64 + ((grp ^ ((l15 >> 1) & 3)) << 4);   // V read base (bytes)

    f32x4 OA[16], OB[16];
    #pragma unroll
    for (int ck = 0; ck < 16; ck++) {
        OA[ck] = (f32x4){0.f,0.f,0.f,0.f};
        OB[ck] = (f32x4){0.f,0.f,0.f,0.f};
    }
    float mA = -1e30f, lA = 0.f, mB = -1e30f, lB = 0.f;

    // prologue: stage chunk 0 into buf 0
    #pragma unroll
    for (int e = 0; e < 4; e++) {
        gload16(kb + (size_t)jlo*CC + koff[e], &bufK[0][(4*w + e)*512]);
        gload16(vb + voff[e] + jlo,            &bufV[0][(4*w + e)*512]);
    }
    __syncthreads();

    int cur = 0;
    for (int t = 0; t < NT; t++) {
        // stage next chunk into the other buffer (loads fly during compute)
        if (t + 1 < NT) {
            int j0n = jlo + (t + 1) * CH;
            #pragma unroll
            for (int e = 0; e < 4; e++) {
                gload16(kb + (size_t)j0n*CC + koff[e], &bufK[cur ^ 1][(4*w + e)*512]);
                gload16(vb + voff[e] + j0n,            &bufV[cur ^ 1][(4*w + e)*512]);
            }
        }
        const char* kbase = (const char*)&bufK[cur][0];
        const char* vbase = (const char*)&bufV[cur][0];

        // QK^T swapped: rows = j, cols = q; each K-frag feeds both q-tiles
        f32x4 sA0 = (f32x4){0.f,0.f,0.f,0.f}, sA1 = (f32x4){0.f,0.f,0.f,0.f};
        f32x4 sB0 = (f32x4){0.f,0.f,0.f,0.f}, sB1 = (f32x4){0.f,0.f,0.f,0.f};
        __builtin_amdgcn_s_setprio(1);
        #pragma unroll
        for (int ck = 0; ck < 8; ck++) {
            int cx = ((ck*64) | g16) ^ krw;
            f16x8 k0 = *(const f16x8*)(kbase + kru + cx);
            f16x8 k1 = *(const f16x8*)(kbase + 8192 + kru + cx);
            sA0 = __builtin_amdgcn_mfma_f32_16x16x32_f16(k0, qfA[ck], sA0, 0, 0, 0);
            sA1 = __builtin_amdgcn_mfma_f32_16x16x32_f16(k1, qfA[ck], sA1, 0, 0, 0);
            sB0 = __builtin_amdgcn_mfma_f32_16x16x32_f16(k0, qfB[ck], sB0, 0, 0, 0);
            sB1 = __builtin_amdgcn_mfma_f32_16x16x32_f16(k1, qfB[ck], sB1, 0, 0, 0);
        }
        __builtin_amdgcn_s_setprio(0);

        // ---- online softmax tile A (exp2 domain; per-lane q = l15) ----
        f16x8 pfA, pfB;
        {
            float x0 = fmaxf(fmaxf(sA0[0], sA0[1]), fmaxf(sA0[2], sA0[3]));
            float x1 = fmaxf(fmaxf(sA1[0], sA1[1]), fmaxf(sA1[2], sA1[3]));
            float mx = fmaxf(x0, x1);
            mx = fmaxf(mx, __shfl_xor(mx, 16));
            mx = fmaxf(mx, __shfl_xor(mx, 32));
            bool up = !__all(mx <= mA);
            if (up) {
                float mn = fmaxf(mA, mx);
                float f = exp2f(mA - mn);
                mA = mn;
                lA *= f;
                int fb = (lane & 48) | (grp << 2);
                float fs0 = __shfl(f, fb),   fs1 = __shfl(f, fb+1);
                float fs2 = __shfl(f, fb+2), fs3 = __shfl(f, fb+3);
                f32x4 fv = (f32x4){fs0, fs1, fs2, fs3};
                #pragma unroll
                for (int ck = 0; ck < 16; ck++) OA[ck] *= fv;
            }
            sA0[0] = exp2f(sA0[0] - mA); sA0[1] = exp2f(sA0[1] - mA);
            sA0[2] = exp2f(sA0[2] - mA); sA0[3] = exp2f(sA0[3] - mA);
            sA1[0] = exp2f(sA1[0] - mA); sA1[1] = exp2f(sA1[1] - mA);
            sA1[2] = exp2f(sA1[2] - mA); sA1[3] = exp2f(sA1[3] - mA);
            float ps = ((sA0[0]+sA0[1]) + (sA0[2]+sA0[3])) + ((sA1[0]+sA1[1]) + (sA1[2]+sA1[3]));
            ps += __shfl_xor(ps, 16);
            ps += __shfl_xor(ps, 32);
            lA += ps;
            unsigned pk0 = pkh2(sA0[0], sA0[1]);
            unsigned pk1 = pkh2(sA0[2], sA0[3]);
            unsigned pk2 = pkh2(sA1[0], sA1[1]);
            unsigned pk3 = pkh2(sA1[2], sA1[3]);
            int srcA = (((grp << 1)    ) & 3) * 16 + l15;
            int srcB = (((grp << 1) + 1) & 3) * 16 + l15;
            bool lo = (grp < 2);
            unsigned u0A = __shfl(pk0, srcA), u2A = __shfl(pk2, srcA);
            unsigned u1A = __shfl(pk1, srcA), u3A = __shfl(pk3, srcA);
            unsigned u0B = __shfl(pk0, srcB), u2B = __shfl(pk2, srcB);
            unsigned u1B = __shfl(pk1, srcB), u3B = __shfl(pk3, srcB);
            uint4 pu;
            pu.x = lo ? u0A : u2A;
            pu.y = lo ? u1A : u3A;
            pu.z = lo ? u0B : u2B;
            pu.w = lo ? u1B : u3B;
            pfA = __builtin_bit_cast(f16x8, pu);
        }
        // ---- online softmax tile B ----
        {
            float x0 = fmaxf(fmaxf(sB0[0], sB0[1]), fmaxf(sB0[2], sB0[3]));
            float x1 = fmaxf(fmaxf(sB1[0], sB1[1]), fmaxf(sB1[2], sB1[3]));
            float mx = fmaxf(x0, x1);
            mx = fmaxf(mx, __shfl_xor(mx, 16));
            mx = fmaxf(mx, __shfl_xor(mx, 32));
            bool up = !__all(mx <= mB);
            if (up) {
                float mn = fmaxf(mB, mx);
                float f = exp2f(mB - mn);
                mB = mn;
                lB *= f;
                int fb = (lane & 48) | (grp << 2);
                float fs0 = __shfl(f, fb),   fs1 = __shfl(f, fb+1);
                float fs2 = __shfl(f, fb+2), fs3 = __shfl(f, fb+3);
                f32x4 fv = (f32x4){fs0, fs1, fs2, fs3};
                #pragma unroll
                for (int ck = 0; ck < 16; ck++) OB[ck] *= fv;
            }
            sB0[0] = exp2f(sB0[0] - mB); sB0[1] = exp2f(sB0[1] - mB);
            sB0[2] = exp2f(sB0[2] - mB); sB0[3] = exp2f(sB0[3] - mB);
            sB1[0] = exp2f(sB1[0] - mB); sB1[1] = exp2f(sB1[1] - mB);
            sB1[2] = exp2f(sB1[2] - mB); sB1[3] = exp2f(sB1[3] - mB);
            float ps = ((sB0[0]+sB0[1]) + (sB0[2]+sB0[3])) + ((sB1[0]+sB1[1]) + (sB1[2]+sB1[3]));
            ps += __shfl_xor(ps, 16);
            ps += __shfl_xor(ps, 32);
            lB += ps;
            unsigned pk0 = pkh2(sB0[0], sB0[1]);
            unsigned pk1 = pkh2(sB0[2], sB0[3]);
            unsigned pk2 = pkh2(sB1[0], sB1[1]);
            unsigned pk3 = pkh2(sB1[2], sB1[3]);
            int srcA = (((grp << 1)    ) & 3) * 16 + l15;
            int srcB = (((grp << 1) + 1) & 3) * 16 + l15;
            bool lo = (grp < 2);
            unsigned u0A = __shfl(pk0, srcA), u2A = __shfl(pk2, srcA);
            unsigned u1A = __shfl(pk1, srcA), u3A = __shfl(pk3, srcA);
            unsigned u0B = __shfl(pk0, srcB), u2B = __shfl(pk2, srcB);
            unsigned u1B = __shfl(pk1, srcB), u3B = __shfl(pk3, srcB);
            uint4 pu;
            pu.x = lo ? u0A : u2A;
            pu.y = lo ? u1A : u3A;
            pu.z = lo ? u0B : u2B;
            pu.w = lo ? u1B : u3B;
            pfB = __builtin_bit_cast(f16x8, pu);
        }
        // PV: each V-frag feeds both q-tiles
        __builtin_amdgcn_s_setprio(1);
        #pragma unroll
        for (int ck = 0; ck < 16; ck++) {
            f16x8 vf = *(const f16x8*)(vbase + ck*1024 + vrb);
            OA[ck] = __builtin_amdgcn_mfma_f32_16x16x32_f16(pfA, vf, OA[ck], 0, 0, 0);
            OB[ck] = __builtin_amdgcn_mfma_f32_16x16x32_f16(pfB, vf, OB[ck], 0, 0, 0);
        }
        __builtin_amdgcn_s_setprio(0);
        __syncthreads();   // drains vmcnt (next-chunk stage) + joins waves
        cur ^= 1;
    }

    // epilogue: normalized partials + (m,l) for both tiles
    float invA = 1.f / lA, invB = 1.f / lB;
    int ib = (lane & 48) | (grp << 2);
    float a0 = __shfl(invA, ib),   a1 = __shfl(invA, ib+1);
    float a2 = __shfl(invA, ib+2), a3 = __shfl(invA, ib+3);
    float b0 = __shfl(invB, ib),   b1 = __shfl(invB, ib+1);
    float b2 = __shfl(invB, ib+2), b3 = __shfl(invB, ib+3);
    unsigned short* po = pO + ((size_t)(s*BB + b)*NN + q0) * CC;
    #pragma unroll
    for (int ck = 0; ck < 16; ck++) {
        po[(size_t)(grp*4+0)*CC + ck*16 + l15] = f2h_bits(OA[ck][0] * a0);
        po[(size_t)(grp*4+1)*CC + ck*16 + l15] = f2h_bits(OA[ck][1] * a1);
        po[(size_t)(grp*4+2)*CC + ck*16 + l15] = f2h_bits(OA[ck][2] * a2);
        po[(size_t)(grp*4+3)*CC + ck*16 + l15] = f2h_bits(OA[ck][3] * a3);
        po[(size_t)(16 + grp*4+0)*CC + ck*16 + l15] = f2h_bits(OB[ck][0] * b0);
        po[(size_t)(16 + grp*4+1)*CC + ck*16 + l15] = f2h_bits(OB[ck][1] * b1);
        po[(size_t)(16 + grp*4+2)*CC + ck*16 + l15] = f2h_bits(OB[ck][2] * b2);
        po[(size_t)(16 + grp*4+3)*CC + ck*16 + l15] = f2h_bits(OB[ck][3] * b3);
    }
    if (lane < 16)
        ml[(size_t)(s*BB + b)*NN + q0 + lane] = make_float2(mA, lA);
    else if (lane < 32)
        ml[(size_t)(s*BB + b)*NN + q0 + 16 + l15] = make_float2(mB, lB);
}

// ------------- Kernel 5b: merge JSPLIT partials -------------
__global__ __launch_bounds__(256) void attn_merge_kernel(
    const unsigned short* __restrict__ pO, const float2* __restrict__ ml,
    unsigned short* __restrict__ aT)
{
    int t = threadIdx.x;
    int qrow = blockIdx.x * 16 + (t >> 4);   // b*NN + q
    int c0 = (t & 15) * 16;
    float M = -1e30f;
    float m8[JSPLIT], l8[JSPLIT];
    #pragma unroll
    for (int s = 0; s < JSPLIT; s++) {
        float2 v = ml[(size_t)s*BB*NN + qrow];
        m8[s] = v.x; l8[s] = v.y;
        M = fmaxf(M, v.x);
    }
    float W = 0.f, wt[JSPLIT];
    #pragma unroll
    for (int s = 0; s < JSPLIT; s++) { wt[s] = l8[s] * exp2f(m8[s] - M); W += wt[s]; }
    float iW = 1.f / W;
    float acc[16];
    #pragma unroll
    for (int e = 0; e < 16; e++) acc[e] = 0.f;
    #pragma unroll
    for (int s = 0; s < JSPLIT; s++) {
        const unsigned short* p = pO + ((size_t)s*BB*NN + qrow)*CC + c0;
        f16x8 a0 = *(const f16x8*)p;
        f16x8 a1 = *(const f16x8*)(p + 8);
        float ws = wt[s] * iW;
        #pragma unroll
        for (int e = 0; e < 8; e++) {
            acc[e]     += ws * (float)a0[e];
            acc[e + 8] += ws * (float)a1[e];
        }
    }
    union { _Float16 h[8]; uint4 u; } o0, o1;
    #pragma unroll
    for (int e = 0; e < 8; e++) { o0.h[e] = (_Float16)acc[e]; o1.h[e] = (_Float16)acc[e+8]; }
    unsigned short* dst = aT + (size_t)qrow*CC + c0;
    *(uint4*)dst = o0.u;
    *(uint4*)(dst + 8) = o1.u;
}

// ------------- Kernel 6: output projection + bias + residual (fp32 out) -------------
__global__ __launch_bounds__(256) void proj_out_kernel(
    const unsigned short* __restrict__ aT,
    const unsigned short* __restrict__ wp16, const float* __restrict__ bp,
    const float* __restrict__ x, float* __restrict__ out)
{
    int b = blockIdx.z;
    int i0 = blockIdx.x * 64, o0 = blockIdx.y * 64;
    int lane = threadIdx.x & 63, wid = threadIdx.x >> 6;
    int col = lane & 15, grp = lane >> 4;
    int ibase = i0 + wid * 16;
    const unsigned short* ab = aT + (size_t)b*NN*CC;
    f32x4 acc[4];
    for (int ot = 0; ot < 4; ot++) acc[ot] = (f32x4){0.f,0.f,0.f,0.f};
    for (int ck = 0; ck < 8; ck++) {
        f16x8 af = *(const f16x8*)(ab + (size_t)(ibase + col)*CC + ck*32 + grp*8);
        for (int ot = 0; ot < 4; ot++) {
            f16x8 bf = *(const f16x8*)(wp16 + (size_t)(o0 + ot*16 + col)*CC + ck*32 + grp*8);
            acc[ot] = __builtin_amdgcn_mfma_f32_16x16x32_f16(af, bf, acc[ot], 0, 0, 0);
        }
    }
    int iw = ibase + grp * 4;
    for (int ot = 0; ot < 4; ot++) {
        int o = o0 + ot*16 + col;
        float bo = bp[o];
        size_t base = (size_t)b*CC*NN + (size_t)o*NN + iw;
        float4 x4 = *(const float4*)(x + base);
        float4 r;
        r.x = x4.x + acc[ot][0] + bo;
        r.y = x4.y + acc[ot][1] + bo;
        r.z = x4.z + acc[ot][2] + bo;
        r.w = x4.w + acc[ot][3] + bo;
        *(float4*)(out + base) = r;
    }
}

extern "C" void kernel_launch(void* const* d_in, const int* in_sizes, int n_in,
                              void* d_out, int out_size, void* d_ws, size_t ws_size,
                              hipStream_t stream) {
    const float* x  = (const float*)d_in[0];
    const float* gs = (const float*)d_in[1];
    const float* gb = (const float*)d_in[2];
    const float* wq = (const float*)d_in[3];
    const float* bq = (const float*)d_in[4];
    const float* wk = (const float*)d_in[5];
    const float* bk = (const float*)d_in[6];
    const float* wv = (const float*)d_in[7];
    const float* bv = (const float*)d_in[8];
    const float* wp = (const float*)d_in[9];
    const float* bp = (const float*)d_in[10];
    float* out = (float*)d_out;

    char* ws = (char*)d_ws;
    const size_t sz = (size_t)BB * NN * CC * sizeof(unsigned short);   // 4 MB
    unsigned short* hT  = (unsigned short*)(ws);
    unsigned short* qT  = (unsigned short*)(ws + sz);
    unsigned short* kT  = (unsigned short*)(ws + 2*sz);
    unsigned short* vC  = (unsigned short*)(ws + 3*sz);
    unsigned short* aT  = (unsigned short*)(ws + 4*sz);
    unsigned short* w16 = (unsigned short*)(ws + 5*sz);                 // 512 KB
    float2* part        = (float2*)(ws + 5*sz + 512*1024);              // 2 KB
    float2* ml          = (float2*)(ws + 5*sz + 768*1024);              // 512 KB
    unsigned short* pO  = (unsigned short*)(ws + 5*sz + 1280*1024);     // 32 MB

    prep_w16_kernel<<<dim3(CC*CC/4/256, 4), 256, 0, stream>>>(wq, wk, wv, wp, w16);
    gn_part_kernel<<<dim3(GG, 4, BB), 256, 0, stream>>>(x, part);
    gn_apply_kernel<<<dim3(NN/64, BB), 256, 0, stream>>>(x, gs, gb, part, hT);
    proj_qk_kernel<<<dim3(NN/64, CC/64, 2*BB), 256, 0, stream>>>(hT, w16, bq, bk, qT, kT);
    proj_v_kernel<<<dim3(NN/64, CC/64, BB), 256, 0, stream>>>(hT, w16 + 2*CC*CC, bv, vC);
    attn_kernel<<<dim3(NN/QTILE, JSPLIT, BB), 256, 0, stream>>>(qT, kT, vC, pO, ml);
    attn_merge_kernel<<<dim3(BB*NN/16), 256, 0, stream>>>(pO, ml, aT);
    proj_out_kernel<<<dim3(NN/64, CC/64, BB), 256, 0, stream>>>(aT, w16 + 3*CC*CC, bp, x, out);
}

// Round 5
// 141.091 us; speedup vs baseline: 2.6934x; 1.0057x over previous
//
#include <hip/hip_runtime.h>
#include <hip/hip_bf16.h>
#include <math.h>

#define BB 2
#define CC 256
#define GG 32
#define NN 4096
#define EPSF 1e-6f
#define JSPLIT 8
#define JBLK (NN / JSPLIT)   // 512 j per block
#define CH 32                // j chunk
#define NT (JBLK / CH)       // 16 chunks
#define QTILE 128            // queries per attn block (4 waves x 32)
#define LOG2E 1.4426950408889634f

typedef _Float16 f16x8 __attribute__((ext_vector_type(8)));
typedef float f32x4 __attribute__((ext_vector_type(4)));

static __device__ __forceinline__ unsigned short f2h_bits(float f) {
    _Float16 h = (_Float16)f;
    return __builtin_bit_cast(unsigned short, h);
}
static __device__ __forceinline__ unsigned pkh2(float a, float b) {
    return __builtin_bit_cast(unsigned, __builtin_amdgcn_cvt_pkrtz(a, b));
}
static __device__ __forceinline__ void gload16(const void* g, void* l) {
    __builtin_amdgcn_global_load_lds(
        (const __attribute__((address_space(1))) void*)g,
        (__attribute__((address_space(3))) void*)l, 16, 0, 0);
}

// ---------------- Kernel 0: weights -> fp16 (wq pre-scaled by c^-0.5 * log2e) ----------------
__global__ __launch_bounds__(256) void prep_w16_kernel(
    const float* __restrict__ wq, const float* __restrict__ wk,
    const float* __restrict__ wv, const float* __restrict__ wp,
    unsigned short* __restrict__ w16)
{
    int m = blockIdx.y;
    const float* src = (m == 0) ? wq : (m == 1) ? wk : (m == 2) ? wv : wp;
    float scale = (m == 0) ? 0.0625f * LOG2E : 1.0f;
    int idx = blockIdx.x * 256 + threadIdx.x;   // unit = 4 floats
    float4 v = ((const float4*)src)[idx];
    union { _Float16 h[4]; uint2 u; } pk;
    pk.h[0] = (_Float16)(v.x * scale);
    pk.h[1] = (_Float16)(v.y * scale);
    pk.h[2] = (_Float16)(v.z * scale);
    pk.h[3] = (_Float16)(v.w * scale);
    *(uint2*)(w16 + (size_t)m * CC * CC + (size_t)idx * 4) = pk.u;
}

// ---------------- Kernel 1: GroupNorm partial sums (4 parts per (b,g)) ----------------
__global__ __launch_bounds__(256) void gn_part_kernel(
    const float* __restrict__ x, float2* __restrict__ part)
{
    int g = blockIdx.x, p = blockIdx.y, b = blockIdx.z;
    const float* base = x + ((size_t)b * CC + (size_t)g * 8) * NN + (size_t)p * 8192;
    int t = threadIdx.x;
    float s = 0.f, ss = 0.f;
    for (int idx = t; idx < 2048; idx += 256) {
        float4 v4 = ((const float4*)base)[idx];
        s  += v4.x + v4.y + v4.z + v4.w;
        ss += v4.x*v4.x + v4.y*v4.y + v4.z*v4.z + v4.w*v4.w;
    }
    for (int off = 32; off; off >>= 1) {
        s  += __shfl_down(s,  off);
        ss += __shfl_down(ss, off);
    }
    __shared__ float red[8];
    int wid = t >> 6;
    if ((t & 63) == 0) { red[wid*2] = s; red[wid*2+1] = ss; }
    __syncthreads();
    if (t == 0) {
        part[(b*GG + g)*4 + p] = make_float2(red[0]+red[2]+red[4]+red[6],
                                             red[1]+red[3]+red[5]+red[7]);
    }
}

// ------------- Kernel 2: fused GN-apply + q/k/v projections -------------
// Block: 32 n-rows x 256 c. x tile is normalized+transposed into a swizzled
// fp16 LDS tile (row stride 512B, 16B blocks XOR'd by row&7), then q,k,v MFMA.
__global__ __launch_bounds__(256) void proj_qkv_kernel(
    const float* __restrict__ x, const float* __restrict__ sc,
    const float* __restrict__ bi, const float2* __restrict__ part,
    const unsigned short* __restrict__ w16,
    const float* __restrict__ bq, const float* __restrict__ bk,
    const float* __restrict__ bv,
    unsigned short* __restrict__ qT, unsigned short* __restrict__ kT,
    unsigned short* __restrict__ vC)
{
    int b  = blockIdx.y;
    int i0 = blockIdx.x * 32;
    int t  = threadIdx.x;
    __shared__ unsigned short htile[32 * 256];   // 16 KB, swizzled
    __shared__ float s_mean[GG], s_rstd[GG], s_sc[CC], s_bi[CC];
    if (t < GG) {
        float2 p0 = part[(b*GG + t)*4 + 0];
        float2 p1 = part[(b*GG + t)*4 + 1];
        float2 p2 = part[(b*GG + t)*4 + 2];
        float2 p3 = part[(b*GG + t)*4 + 3];
        float S  = p0.x + p1.x + p2.x + p3.x;
        float SS = p0.y + p1.y + p2.y + p3.y;
        float mean = S / 32768.f;
        float var  = SS / 32768.f - mean * mean;
        s_mean[t] = mean;
        s_rstd[t] = rsqrtf(var + EPSF);
    }
    s_sc[t] = sc[t];
    s_bi[t] = bi[t];
    __syncthreads();

    // fill: thread covers n-quad (t&7)*4, c-quads (t>>3)*4 and +128
    char* hw = (char*)htile;
    int nq = (t & 7) * 4;
    int cq = (t >> 3) * 4;
    #pragma unroll
    for (int k = 0; k < 2; k++) {
        int c0 = cq + k * 128;
        float4 xr[4];
        float aa[4], dd[4];
        #pragma unroll
        for (int e = 0; e < 4; e++) {
            int c = c0 + e;
            xr[e] = *(const float4*)(x + ((size_t)b*CC + c)*NN + i0 + nq);
            aa[e] = s_rstd[c >> 3] * s_sc[c];
            dd[e] = s_bi[c] - s_mean[c >> 3] * aa[e];
        }
        #pragma unroll
        for (int j = 0; j < 4; j++) {
            int row = nq + j;
            union { _Float16 h[4]; uint2 u; } pk;
            pk.h[0] = (_Float16)(((const float*)&xr[0])[j] * aa[0] + dd[0]);
            pk.h[1] = (_Float16)(((const float*)&xr[1])[j] * aa[1] + dd[1]);
            pk.h[2] = (_Float16)(((const float*)&xr[2])[j] * aa[2] + dd[2]);
            pk.h[3] = (_Float16)(((const float*)&xr[3])[j] * aa[3] + dd[3]);
            int off = row*512 + (((c0 >> 3) ^ (row & 7)) << 4) + (c0 & 7) * 2;
            *(uint2*)(hw + off) = pk.u;
        }
    }
    __syncthreads();

    int lane = t & 63, w = t >> 6;
    int col = lane & 15, grp = lane >> 4;
    const char* hr = (const char*)htile;

    // q, k: wave owns o-subtile w*16 of each 64-o group; i tiles it=0..1
    #pragma unroll
    for (int p = 0; p < 2; p++) {
        const unsigned short* wgt = w16 + (size_t)p * CC * CC;
        const float* bias = p ? bk : bq;
        unsigned short* outp = (p ? kT : qT) + (size_t)b * NN * CC;
        float osc = p ? 1.0f : 0.0625f * LOG2E;
        #pragma unroll
        for (int ot = 0; ot < 4; ot++) {
            int ow = ot * 64 + w * 16;
            f32x4 acc[2];
            acc[0] = (f32x4){0.f,0.f,0.f,0.f};
            acc[1] = (f32x4){0.f,0.f,0.f,0.f};
            #pragma unroll
            for (int ck = 0; ck < 8; ck++) {
                f16x8 af = *(const f16x8*)(wgt + (size_t)(ow + col)*CC + ck*32 + grp*8);
                #pragma unroll
                for (int it = 0; it < 2; it++) {
                    int row = it*16 + col;
                    f16x8 bf = *(const f16x8*)(hr + row*512 + (((ck*4 + grp) ^ (row & 7)) << 4));
                    acc[it] = __builtin_amdgcn_mfma_f32_16x16x32_f16(af, bf, acc[it], 0, 0, 0);
                }
            }
            int obase = ow + grp * 4;
            float b0 = bias[obase]*osc, b1 = bias[obase+1]*osc,
                  b2 = bias[obase+2]*osc, b3 = bias[obase+3]*osc;
            #pragma unroll
            for (int it = 0; it < 2; it++) {
                int i = i0 + it*16 + col;
                union { _Float16 h[4]; uint2 u; } pk;
                pk.h[0] = (_Float16)(acc[it][0] + b0);
                pk.h[1] = (_Float16)(acc[it][1] + b1);
                pk.h[2] = (_Float16)(acc[it][2] + b2);
                pk.h[3] = (_Float16)(acc[it][3] + b3);
                *(uint2*)(outp + (size_t)i*CC + obase) = pk.u;
            }
        }
    }
    // v: (c, n) layout. wave w: i-subtile (w&1)*16, o-groups (w>>1)*2 + {0,1}
    {
        const unsigned short* wgt = w16 + (size_t)2 * CC * CC;
        unsigned short* outp = vC + (size_t)b * CC * NN;
        int ibase = (w & 1) * 16;
        #pragma unroll
        for (int gg = 0; gg < 2; gg++) {
            int og = (w >> 1) * 2 + gg;
            f32x4 acc[4];
            #pragma unroll
            for (int ot = 0; ot < 4; ot++) acc[ot] = (f32x4){0.f,0.f,0.f,0.f};
            #pragma unroll
            for (int ck = 0; ck < 8; ck++) {
                int row = ibase + col;
                f16x8 af = *(const f16x8*)(hr + row*512 + (((ck*4 + grp) ^ (row & 7)) << 4));
                #pragma unroll
                for (int ot = 0; ot < 4; ot++) {
                    f16x8 bf = *(const f16x8*)(wgt + (size_t)(og*64 + ot*16 + col)*CC + ck*32 + grp*8);
                    acc[ot] = __builtin_amdgcn_mfma_f32_16x16x32_f16(af, bf, acc[ot], 0, 0, 0);
                }
            }
            int iw = i0 + ibase + grp * 4;
            #pragma unroll
            for (int ot = 0; ot < 4; ot++) {
                int o = og*64 + ot*16 + col;
                float bo = bv[o];
                union { _Float16 h[4]; uint2 u; } pk;
                pk.h[0] = (_Float16)(acc[ot][0] + bo);
                pk.h[1] = (_Float16)(acc[ot][1] + bo);
                pk.h[2] = (_Float16)(acc[ot][2] + bo);
                pk.h[3] = (_Float16)(acc[ot][3] + bo);
                *(uint2*)(outp + (size_t)o*NN + iw) = pk.u;
            }
        }
    }
}

// ------------- Kernel 3: flash attention, counted-vmcnt two-phase pipeline -------------
// Block: 4 waves x 32q = 128 queries, j-range 512 (JSPLIT=8). LDS 64 KB:
// K[2][32j][256c] rows 512B XOR-swizzled; V[2][256c][32j] rows 64B swizzled.
// Stagger: V(t+1) issued at top of phase A(t); K(t+2) at top of phase B(t).
// Raw s_barrier + s_waitcnt vmcnt(8) at phase boundaries (never 0 mid-loop).
#define WAITV(n) asm volatile("s_waitcnt vmcnt(" #n ")" ::: "memory")
#define SBAR() do { __builtin_amdgcn_sched_barrier(0); __builtin_amdgcn_s_barrier(); \
                    __builtin_amdgcn_sched_barrier(0); } while (0)
#define STAGE_K(tt, bb) do { int _j = jlo + (tt)*CH; _Pragma("unroll") \
    for (int e = 0; e < 4; e++) gload16(kb + (size_t)_j*CC + koff[e], &bufK[bb][(4*w + e)*512]); } while (0)
#define STAGE_V(tt, bb) do { int _j = jlo + (tt)*CH; _Pragma("unroll") \
    for (int e = 0; e < 4; e++) gload16(vb + voff[e] + _j, &bufV[bb][(4*w + e)*512]); } while (0)

__global__ __launch_bounds__(256, 2) void attn_kernel(
    const unsigned short* __restrict__ qT,
    const unsigned short* __restrict__ kT,
    const unsigned short* __restrict__ vC,
    unsigned short* __restrict__ pO,
    float2* __restrict__ ml)
{
    int qt = blockIdx.x, s = blockIdx.y, b = blockIdx.z;
    int tid = threadIdx.x, w = tid >> 6, lane = tid & 63;
    int l15 = lane & 15, grp = lane >> 4;
    int q0 = qt * QTILE + w * 32;
    int jlo = s * JBLK;

    __shared__ unsigned short bufK[2][8192];   // 2 x 16 KB
    __shared__ unsigned short bufV[2][8192];   // 2 x 16 KB

    const unsigned short* qb = qT + (size_t)b * NN * CC;
    const unsigned short* kb = kT + (size_t)b * NN * CC;
    const unsigned short* vb = vC + (size_t)b * CC * NN;

    f16x8 qfA[8], qfB[8];
    #pragma unroll
    for (int ck = 0; ck < 8; ck++) {
        qfA[ck] = *(const f16x8*)(qb + (size_t)(q0 + l15)*CC + ck*32 + grp*8);
        qfB[ck] = *(const f16x8*)(qb + (size_t)(q0 + 16 + l15)*CC + ck*32 + grp*8);
    }

    int koff[4], voff[4];
    #pragma unroll
    for (int e = 0; e < 4; e++) {
        int blk = (4*w + e)*64 + lane;
        int kj = blk >> 5, kcb = blk & 31;
        koff[e] = kj*CC + ((kcb ^ (kj & 7)) * 8);
        int vc = blk >> 2, vcb = blk & 3;
        voff[e] = vc*NN + ((vcb ^ ((vc >> 1) & 3)) * 8);
    }
    int kru = l15 * 512;
    int krw = (l15 & 7) << 4;
    int g16 = grp << 4;
    int vrb = l15*64 + ((grp ^ ((l15 >> 1) & 3)) << 4);

    f32x4 OA[16], OB[16];
    #pragma unroll
    for (int ck = 0; ck < 16; ck++) {
        OA[ck] = (f32x4){0.f,0.f,0.f,0.f};
        OB[ck] = (f32x4){0.f,0.f,0.f,0.f};
    }
    float mA = -1e30f, lA = 0.f, mB = -1e30f, lB = 0.f;

    // prologue: K(0), V(0), K(1)  (issue order matters for counted waits)
    STAGE_K(0, 0);
    STAGE_V(0, 0);
    STAGE_K(1, 1);

    for (int t = 0; t < NT; t++) {
        int cur = t & 1;
        // ---- top of chunk: need K(t); 8 newer loads may stay in flight ----
        if (t < NT - 1) WAITV(8); else WAITV(4);
        SBAR();
        if (t + 1 < NT) STAGE_V(t + 1, cur ^ 1);

        const char* kbase = (const char*)&bufK[cur][0];
        const char* vbase = (const char*)&bufV[cur][0];

        f32x4 sA0 = (f32x4){0.f,0.f,0.f,0.f}, sA1 = (f32x4){0.f,0.f,0.f,0.f};
        f32x4 sB0 = (f32x4){0.f,0.f,0.f,0.f}, sB1 = (f32x4){0.f,0.f,0.f,0.f};
        __builtin_amdgcn_s_setprio(1);
        #pragma unroll
        for (int ck = 0; ck < 8; ck++) {
            int cx = ((ck*64) | g16) ^ krw;
            f16x8 k0 = *(const f16x8*)(kbase + kru + cx);
            f16x8 k1 = *(const f16x8*)(kbase + 8192 + kru + cx);
            sA0 = __builtin_amdgcn_mfma_f32_16x16x32_f16(k0, qfA[ck], sA0, 0, 0, 0);
            sA1 = __builtin_amdgcn_mfma_f32_16x16x32_f16(k1, qfA[ck], sA1, 0, 0, 0);
            sB0 = __builtin_amdgcn_mfma_f32_16x16x32_f16(k0, qfB[ck], sB0, 0, 0, 0);
            sB1 = __builtin_amdgcn_mfma_f32_16x16x32_f16(k1, qfB[ck], sB1, 0, 0, 0);
        }
        __builtin_amdgcn_s_setprio(0);

        f16x8 pfA, pfB;
        {   // ---- online softmax tile A ----
            float x0 = fmaxf(fmaxf(sA0[0], sA0[1]), fmaxf(sA0[2], sA0[3]));
            float x1 = fmaxf(fmaxf(sA1[0], sA1[1]), fmaxf(sA1[2], sA1[3]));
            float mx = fmaxf(x0, x1);
            mx = fmaxf(mx, __shfl_xor(mx, 16));
            mx = fmaxf(mx, __shfl_xor(mx, 32));
            bool up = !__all(mx <= mA);
            if (up) {
                float mn = fmaxf(mA, mx);
                float f = exp2f(mA - mn);
                mA = mn;
                lA *= f;
                int fb = (lane & 48) | (grp << 2);
                float fs0 = __shfl(f, fb),   fs1 = __shfl(f, fb+1);
                float fs2 = __shfl(f, fb+2), fs3 = __shfl(f, fb+3);
                f32x4 fv = (f32x4){fs0, fs1, fs2, fs3};
                #pragma unroll
                for (int ck = 0; ck < 16; ck++) OA[ck] *= fv;
            }
            sA0[0] = exp2f(sA0[0] - mA); sA0[1] = exp2f(sA0[1] - mA);
            sA0[2] = exp2f(sA0[2] - mA); sA0[3] = exp2f(sA0[3] - mA);
            sA1[0] = exp2f(sA1[0] - mA); sA1[1] = exp2f(sA1[1] - mA);
            sA1[2] = exp2f(sA1[2] - mA); sA1[3] = exp2f(sA1[3] - mA);
            float ps = ((sA0[0]+sA0[1]) + (sA0[2]+sA0[3])) + ((sA1[0]+sA1[1]) + (sA1[2]+sA1[3]));
            ps += __shfl_xor(ps, 16);
            ps += __shfl_xor(ps, 32);
            lA += ps;
            unsigned pk0 = pkh2(sA0[0], sA0[1]);
            unsigned pk1 = pkh2(sA0[2], sA0[3]);
            unsigned pk2 = pkh2(sA1[0], sA1[1]);
            unsigned pk3 = pkh2(sA1[2], sA1[3]);
            int srcA = (((grp << 1)    ) & 3) * 16 + l15;
            int srcB = (((grp << 1) + 1) & 3) * 16 + l15;
            bool lo = (grp < 2);
            unsigned u0A = __shfl(pk0, srcA), u2A = __shfl(pk2, srcA);
            unsigned u1A = __shfl(pk1, srcA), u3A = __shfl(pk3, srcA);
            unsigned u0B = __shfl(pk0, srcB), u2B = __shfl(pk2, srcB);
            unsigned u1B = __shfl(pk1, srcB), u3B = __shfl(pk3, srcB);
            uint4 pu;
            pu.x = lo ? u0A : u2A;
            pu.y = lo ? u1A : u3A;
            pu.z = lo ? u0B : u2B;
            pu.w = lo ? u1B : u3B;
            pfA = __builtin_bit_cast(f16x8, pu);
        }
        {   // ---- online softmax tile B ----
            float x0 = fmaxf(fmaxf(sB0[0], sB0[1]), fmaxf(sB0[2], sB0[3]));
            float x1 = fmaxf(fmaxf(sB1[0], sB1[1]), fmaxf(sB1[2], sB1[3]));
            float mx = fmaxf(x0, x1);
            mx = fmaxf(mx, __shfl_xor(mx, 16));
            mx = fmaxf(mx, __shfl_xor(mx, 32));
            bool up = !__all(mx <= mB);
            if (up) {
                float mn = fmaxf(mB, mx);
                float f = exp2f(mB - mn);
                mB = mn;
                lB *= f;
                int fb = (lane & 48) | (grp << 2);
                float fs0 = __shfl(f, fb),   fs1 = __shfl(f, fb+1);
                float fs2 = __shfl(f, fb+2), fs3 = __shfl(f, fb+3);
                f32x4 fv = (f32x4){fs0, fs1, fs2, fs3};
                #pragma unroll
                for (int ck = 0; ck < 16; ck++) OB[ck] *= fv;
            }
            sB0[0] = exp2f(sB0[0] - mB); sB0[1] = exp2f(sB0[1] - mB);
            sB0[2] = exp2f(sB0[2] - mB); sB0[3] = exp2f(sB0[3] - mB);
            sB1[0] = exp2f(sB1[0] - mB); sB1[1] = exp2f(sB1[1] - mB);
            sB1[2] = exp2f(sB1[2] - mB); sB1[3] = exp2f(sB1[3] - mB);
            float ps = ((sB0[0]+sB0[1]) + (sB0[2]+sB0[3])) + ((sB1[0]+sB1[1]) + (sB1[2]+sB1[3]));
            ps += __shfl_xor(ps, 16);
            ps += __shfl_xor(ps, 32);
            lB += ps;
            unsigned pk0 = pkh2(sB0[0], sB0[1]);
            unsigned pk1 = pkh2(sB0[2], sB0[3]);
            unsigned pk2 = pkh2(sB1[0], sB1[1]);
            unsigned pk3 = pkh2(sB1[2], sB1[3]);
            int srcA = (((grp << 1)    ) & 3) * 16 + l15;
            int srcB = (((grp << 1) + 1) & 3) * 16 + l15;
            bool lo = (grp < 2);
            unsigned u0A = __shfl(pk0, srcA), u2A = __shfl(pk2, srcA);
            unsigned u1A = __shfl(pk1, srcA), u3A = __shfl(pk3, srcA);
            unsigned u0B = __shfl(pk0, srcB), u2B = __shfl(pk2, srcB);
            unsigned u1B = __shfl(pk1, srcB), u3B = __shfl(pk3, srcB);
            uint4 pu;
            pu.x = lo ? u0A : u2A;
            pu.y = lo ? u1A : u3A;
            pu.z = lo ? u0B : u2B;
            pu.w = lo ? u1B : u3B;
            pfB = __builtin_bit_cast(f16x8, pu);
        }

        // ---- mid barrier: need V(t); K(t+1)/V(t+1) stay in flight ----
        if (t < NT - 1) WAITV(8); else WAITV(0);
        SBAR();
        if (t + 2 < NT) STAGE_K(t + 2, cur);   // (t+2)&1 == cur

        __builtin_amdgcn_s_setprio(1);
        #pragma unroll
        for (int ck = 0; ck < 16; ck++) {
            f16x8 vf = *(const f16x8*)(vbase + ck*1024 + vrb);
            OA[ck] = __builtin_amdgcn_mfma_f32_16x16x32_f16(pfA, vf, OA[ck], 0, 0, 0);
            OB[ck] = __builtin_amdgcn_mfma_f32_16x16x32_f16(pfB, vf, OB[ck], 0, 0, 0);
        }
        __builtin_amdgcn_s_setprio(0);
    }

    // epilogue: normalized partials + (m,l) for both tiles
    float invA = 1.f / lA, invB = 1.f / lB;
    int ib = (lane & 48) | (grp << 2);
    float a0 = __shfl(invA, ib),   a1 = __shfl(invA, ib+1);
    float a2 = __shfl(invA, ib+2), a3 = __shfl(invA, ib+3);
    float b0 = __shfl(invB, ib),   b1 = __shfl(invB, ib+1);
    float b2 = __shfl(invB, ib+2), b3 = __shfl(invB, ib+3);
    unsigned short* po = pO + ((size_t)(s*BB + b)*NN + q0) * CC;
    #pragma unroll
    for (int ck = 0; ck < 16; ck++) {
        po[(size_t)(grp*4+0)*CC + ck*16 + l15] = f2h_bits(OA[ck][0] * a0);
        po[(size_t)(grp*4+1)*CC + ck*16 + l15] = f2h_bits(OA[ck][1] * a1);
        po[(size_t)(grp*4+2)*CC + ck*16 + l15] = f2h_bits(OA[ck][2] * a2);
        po[(size_t)(grp*4+3)*CC + ck*16 + l15] = f2h_bits(OA[ck][3] * a3);
        po[(size_t)(16 + grp*4+0)*CC + ck*16 + l15] = f2h_bits(OB[ck][0] * b0);
        po[(size_t)(16 + grp*4+1)*CC + ck*16 + l15] = f2h_bits(OB[ck][1] * b1);
        po[(size_t)(16 + grp*4+2)*CC + ck*16 + l15] = f2h_bits(OB[ck][2] * b2);
        po[(size_t)(16 + grp*4+3)*CC + ck*16 + l15] = f2h_bits(OB[ck][3] * b3);
    }
    if (lane < 16)
        ml[(size_t)(s*BB + b)*NN + q0 + lane] = make_float2(mA, lA);
    else if (lane < 32)
        ml[(size_t)(s*BB + b)*NN + q0 + 16 + l15] = make_float2(mB, lB);
}

// ------------- Kernel 3b: merge JSPLIT partials -------------
__global__ __launch_bounds__(256) void attn_merge_kernel(
    const unsigned short* __restrict__ pO, const float2* __restrict__ ml,
    unsigned short* __restrict__ aT)
{
    int t = threadIdx.x;
    int qrow = blockIdx.x * 16 + (t >> 4);   // b*NN + q
    int c0 = (t & 15) * 16;
    float M = -1e30f;
    float m8[JSPLIT], l8[JSPLIT];
    #pragma unroll
    for (int s = 0; s < JSPLIT; s++) {
        float2 v = ml[(size_t)s*BB*NN + qrow];
        m8[s] = v.x; l8[s] = v.y;
        M = fmaxf(M, v.x);
    }
    float W = 0.f, wt[JSPLIT];
    #pragma unroll
    for (int s = 0; s < JSPLIT; s++) { wt[s] = l8[s] * exp2f(m8[s] - M); W += wt[s]; }
    float iW = 1.f / W;
    float acc[16];
    #pragma unroll
    for (int e = 0; e < 16; e++) acc[e] = 0.f;
    #pragma unroll
    for (int s = 0; s < JSPLIT; s++) {
        const unsigned short* p = pO + ((size_t)s*BB*NN + qrow)*CC + c0;
        f16x8 a0 = *(const f16x8*)p;
        f16x8 a1 = *(const f16x8*)(p + 8);
        float ws = wt[s] * iW;
        #pragma unroll
        for (int e = 0; e < 8; e++) {
            acc[e]     += ws * (float)a0[e];
            acc[e + 8] += ws * (float)a1[e];
        }
    }
    union { _Float16 h[8]; uint4 u; } o0, o1;
    #pragma unroll
    for (int e = 0; e < 8; e++) { o0.h[e] = (_Float16)acc[e]; o1.h[e] = (_Float16)acc[e+8]; }
    unsigned short* dst = aT + (size_t)qrow*CC + c0;
    *(uint4*)dst = o0.u;
    *(uint4*)(dst + 8) = o1.u;
}

// ------------- Kernel 4: output projection + bias + residual (fp32 out) -------------
__global__ __launch_bounds__(256) void proj_out_kernel(
    const unsigned short* __restrict__ aT,
    const unsigned short* __restrict__ wp16, const float* __restrict__ bp,
    const float* __restrict__ x, float* __restrict__ out)
{
    int b = blockIdx.z;
    int i0 = blockIdx.x * 64, o0 = blockIdx.y * 64;
    int lane = threadIdx.x & 63, wid = threadIdx.x >> 6;
    int col = lane & 15, grp = lane >> 4;
    int ibase = i0 + wid * 16;
    const unsigned short* ab = aT + (size_t)b*NN*CC;
    f32x4 acc[4];
    for (int ot = 0; ot < 4; ot++) acc[ot] = (f32x4){0.f,0.f,0.f,0.f};
    for (int ck = 0; ck < 8; ck++) {
        f16x8 af = *(const f16x8*)(ab + (size_t)(ibase + col)*CC + ck*32 + grp*8);
        for (int ot = 0; ot < 4; ot++) {
            f16x8 bf = *(const f16x8*)(wp16 + (size_t)(o0 + ot*16 + col)*CC + ck*32 + grp*8);
            acc[ot] = __builtin_amdgcn_mfma_f32_16x16x32_f16(af, bf, acc[ot], 0, 0, 0);
        }
    }
    int iw = ibase + grp * 4;
    for (int ot = 0; ot < 4; ot++) {
        int o = o0 + ot*16 + col;
        float bo = bp[o];
        size_t base = (size_t)b*CC*NN + (size_t)o*NN + iw;
        float4 x4 = *(const float4*)(x + base);
        float4 r;
        r.x = x4.x + acc[ot][0] + bo;
        r.y = x4.y + acc[ot][1] + bo;
        r.z = x4.z + acc[ot][2] + bo;
        r.w = x4.w + acc[ot][3] + bo;
        *(float4*)(out + base) = r;
    }
}

extern "C" void kernel_launch(void* const* d_in, const int* in_sizes, int n_in,
                              void* d_out, int out_size, void* d_ws, size_t ws_size,
                              hipStream_t stream) {
    const float* x  = (const float*)d_in[0];
    const float* gs = (const float*)d_in[1];
    const float* gb = (const float*)d_in[2];
    const float* wq = (const float*)d_in[3];
    const float* bq = (const float*)d_in[4];
    const float* wk = (const float*)d_in[5];
    const float* bk = (const float*)d_in[6];
    const float* wv = (const float*)d_in[7];
    const float* bv = (const float*)d_in[8];
    const float* wp = (const float*)d_in[9];
    const float* bp = (const float*)d_in[10];
    float* out = (float*)d_out;

    char* ws = (char*)d_ws;
    const size_t sz = (size_t)BB * NN * CC * sizeof(unsigned short);   // 4 MB
    unsigned short* qT  = (unsigned short*)(ws + sz);
    unsigned short* kT  = (unsigned short*)(ws + 2*sz);
    unsigned short* vC  = (unsigned short*)(ws + 3*sz);
    unsigned short* aT  = (unsigned short*)(ws + 4*sz);
    unsigned short* w16 = (unsigned short*)(ws + 5*sz);                 // 512 KB
    float2* part        = (float2*)(ws + 5*sz + 512*1024);              // 2 KB
    float2* ml          = (float2*)(ws + 5*sz + 768*1024);              // 512 KB
    unsigned short* pO  = (unsigned short*)(ws + 5*sz + 1280*1024);     // 32 MB

    prep_w16_kernel<<<dim3(CC*CC/4/256, 4), 256, 0, stream>>>(wq, wk, wv, wp, w16);
    gn_part_kernel<<<dim3(GG, 4, BB), 256, 0, stream>>>(x, part);
    proj_qkv_kernel<<<dim3(NN/32, BB), 256, 0, stream>>>(x, gs, gb, part, w16,
                                                         bq, bk, bv, qT, kT, vC);
    attn_kernel<<<dim3(NN/QTILE, JSPLIT, BB), 256, 0, stream>>>(qT, kT, vC, pO, ml);
    attn_merge_kernel<<<dim3(BB*NN/16), 256, 0, stream>>>(pO, ml, aT);
    proj_out_kernel<<<dim3(NN/64, CC/64, BB), 256, 0, stream>>>(aT, w16 + 3*CC*CC, bp, x, out);
}

// Round 8
// 124.963 us; speedup vs baseline: 3.0410x; 1.1291x over previous
//
#include <hip/hip_runtime.h>
#include <hip/hip_bf16.h>
#include <math.h>

#define BB 2
#define CC 256
#define GG 32
#define NN 4096
#define EPSF 1e-6f
#define JSPLIT 8
#define JBLK (NN / JSPLIT)   // 512 j per block
#define CH 32                // j chunk
#define NT (JBLK / CH)       // 16 chunks
#define QTILE 128            // queries per attn block (4 waves x 32)
#define LOG2E 1.4426950408889634f

typedef _Float16 f16x8 __attribute__((ext_vector_type(8)));
typedef float f32x4 __attribute__((ext_vector_type(4)));
typedef float f32x16 __attribute__((ext_vector_type(16)));

static __device__ __forceinline__ unsigned short f2h_bits(float f) {
    _Float16 h = (_Float16)f;
    return __builtin_bit_cast(unsigned short, h);
}
static __device__ __forceinline__ unsigned pkh2(float a, float b) {
    return __builtin_bit_cast(unsigned, __builtin_amdgcn_cvt_pkrtz(a, b));
}
static __device__ __forceinline__ void gload16(const void* g, void* l) {
    __builtin_amdgcn_global_load_lds(
        (const __attribute__((address_space(1))) void*)g,
        (__attribute__((address_space(3))) void*)l, 16, 0, 0);
}

// ---------------- Kernel 0: weights -> fp16 (wq pre-scaled by c^-0.5 * log2e) ----------------
__global__ __launch_bounds__(256) void prep_w16_kernel(
    const float* __restrict__ wq, const float* __restrict__ wk,
    const float* __restrict__ wv, const float* __restrict__ wp,
    unsigned short* __restrict__ w16)
{
    int m = blockIdx.y;
    const float* src = (m == 0) ? wq : (m == 1) ? wk : (m == 2) ? wv : wp;
    float scale = (m == 0) ? 0.0625f * LOG2E : 1.0f;
    int idx = blockIdx.x * 256 + threadIdx.x;   // unit = 4 floats
    float4 v = ((const float4*)src)[idx];
    union { _Float16 h[4]; uint2 u; } pk;
    pk.h[0] = (_Float16)(v.x * scale);
    pk.h[1] = (_Float16)(v.y * scale);
    pk.h[2] = (_Float16)(v.z * scale);
    pk.h[3] = (_Float16)(v.w * scale);
    *(uint2*)(w16 + (size_t)m * CC * CC + (size_t)idx * 4) = pk.u;
}

// ---------------- Kernel 1: GroupNorm partial sums (4 parts per (b,g)) ----------------
__global__ __launch_bounds__(256) void gn_part_kernel(
    const float* __restrict__ x, float2* __restrict__ part)
{
    int g = blockIdx.x, p = blockIdx.y, b = blockIdx.z;
    const float* base = x + ((size_t)b * CC + (size_t)g * 8) * NN + (size_t)p * 8192;
    int t = threadIdx.x;
    float s = 0.f, ss = 0.f;
    for (int idx = t; idx < 2048; idx += 256) {
        float4 v4 = ((const float4*)base)[idx];
        s  += v4.x + v4.y + v4.z + v4.w;
        ss += v4.x*v4.x + v4.y*v4.y + v4.z*v4.z + v4.w*v4.w;
    }
    for (int off = 32; off; off >>= 1) {
        s  += __shfl_down(s,  off);
        ss += __shfl_down(ss, off);
    }
    __shared__ float red[8];
    int wid = t >> 6;
    if ((t & 63) == 0) { red[wid*2] = s; red[wid*2+1] = ss; }
    __syncthreads();
    if (t == 0) {
        part[(b*GG + g)*4 + p] = make_float2(red[0]+red[2]+red[4]+red[6],
                                             red[1]+red[3]+red[5]+red[7]);
    }
}

// ------------- Kernel 2: fused GN-apply + q/k/v projections (round-5 verified) -------------
__global__ __launch_bounds__(256) void proj_qkv_kernel(
    const float* __restrict__ x, const float* __restrict__ sc,
    const float* __restrict__ bi, const float2* __restrict__ part,
    const unsigned short* __restrict__ w16,
    const float* __restrict__ bq, const float* __restrict__ bk,
    const float* __restrict__ bv,
    unsigned short* __restrict__ qT, unsigned short* __restrict__ kT,
    unsigned short* __restrict__ vC)
{
    int b  = blockIdx.y;
    int i0 = blockIdx.x * 32;
    int t  = threadIdx.x;
    __shared__ unsigned short htile[32 * 256];   // 16 KB, swizzled
    __shared__ float s_mean[GG], s_rstd[GG], s_sc[CC], s_bi[CC];
    if (t < GG) {
        float2 p0 = part[(b*GG + t)*4 + 0];
        float2 p1 = part[(b*GG + t)*4 + 1];
        float2 p2 = part[(b*GG + t)*4 + 2];
        float2 p3 = part[(b*GG + t)*4 + 3];
        float S  = p0.x + p1.x + p2.x + p3.x;
        float SS = p0.y + p1.y + p2.y + p3.y;
        float mean = S / 32768.f;
        float var  = SS / 32768.f - mean * mean;
        s_mean[t] = mean;
        s_rstd[t] = rsqrtf(var + EPSF);
    }
    s_sc[t] = sc[t];
    s_bi[t] = bi[t];
    __syncthreads();

    char* hw = (char*)htile;
    int nq = (t & 7) * 4;
    int cq = (t >> 3) * 4;
    #pragma unroll
    for (int k = 0; k < 2; k++) {
        int c0 = cq + k * 128;
        float4 xr[4];
        float aa[4], dd[4];
        #pragma unroll
        for (int e = 0; e < 4; e++) {
            int c = c0 + e;
            xr[e] = *(const float4*)(x + ((size_t)b*CC + c)*NN + i0 + nq);
            aa[e] = s_rstd[c >> 3] * s_sc[c];
            dd[e] = s_bi[c] - s_mean[c >> 3] * aa[e];
        }
        #pragma unroll
        for (int j = 0; j < 4; j++) {
            int row = nq + j;
            union { _Float16 h[4]; uint2 u; } pk;
            pk.h[0] = (_Float16)(((const float*)&xr[0])[j] * aa[0] + dd[0]);
            pk.h[1] = (_Float16)(((const float*)&xr[1])[j] * aa[1] + dd[1]);
            pk.h[2] = (_Float16)(((const float*)&xr[2])[j] * aa[2] + dd[2]);
            pk.h[3] = (_Float16)(((const float*)&xr[3])[j] * aa[3] + dd[3]);
            int off = row*512 + (((c0 >> 3) ^ (row & 7)) << 4) + (c0 & 7) * 2;
            *(uint2*)(hw + off) = pk.u;
        }
    }
    __syncthreads();

    int lane = t & 63, w = t >> 6;
    int col = lane & 15, grp = lane >> 4;
    const char* hr = (const char*)htile;

    #pragma unroll
    for (int p = 0; p < 2; p++) {
        const unsigned short* wgt = w16 + (size_t)p * CC * CC;
        const float* bias = p ? bk : bq;
        unsigned short* outp = (p ? kT : qT) + (size_t)b * NN * CC;
        float osc = p ? 1.0f : 0.0625f * LOG2E;
        #pragma unroll
        for (int ot = 0; ot < 4; ot++) {
            int ow = ot * 64 + w * 16;
            f32x4 acc[2];
            acc[0] = (f32x4){0.f,0.f,0.f,0.f};
            acc[1] = (f32x4){0.f,0.f,0.f,0.f};
            #pragma unroll
            for (int ck = 0; ck < 8; ck++) {
                f16x8 af = *(const f16x8*)(wgt + (size_t)(ow + col)*CC + ck*32 + grp*8);
                #pragma unroll
                for (int it = 0; it < 2; it++) {
                    int row = it*16 + col;
                    f16x8 bf = *(const f16x8*)(hr + row*512 + (((ck*4 + grp) ^ (row & 7)) << 4));
                    acc[it] = __builtin_amdgcn_mfma_f32_16x16x32_f16(af, bf, acc[it], 0, 0, 0);
                }
            }
            int obase = ow + grp * 4;
            float b0 = bias[obase]*osc, b1 = bias[obase+1]*osc,
                  b2 = bias[obase+2]*osc, b3 = bias[obase+3]*osc;
            #pragma unroll
            for (int it = 0; it < 2; it++) {
                int i = i0 + it*16 + col;
                union { _Float16 h[4]; uint2 u; } pk;
                pk.h[0] = (_Float16)(acc[it][0] + b0);
                pk.h[1] = (_Float16)(acc[it][1] + b1);
                pk.h[2] = (_Float16)(acc[it][2] + b2);
                pk.h[3] = (_Float16)(acc[it][3] + b3);
                *(uint2*)(outp + (size_t)i*CC + obase) = pk.u;
            }
        }
    }
    {
        const unsigned short* wgt = w16 + (size_t)2 * CC * CC;
        unsigned short* outp = vC + (size_t)b * CC * NN;
        int ibase = (w & 1) * 16;
        #pragma unroll
        for (int gg = 0; gg < 2; gg++) {
            int og = (w >> 1) * 2 + gg;
            f32x4 acc[4];
            #pragma unroll
            for (int ot = 0; ot < 4; ot++) acc[ot] = (f32x4){0.f,0.f,0.f,0.f};
            #pragma unroll
            for (int ck = 0; ck < 8; ck++) {
                int row = ibase + col;
                f16x8 af = *(const f16x8*)(hr + row*512 + (((ck*4 + grp) ^ (row & 7)) << 4));
                #pragma unroll
                for (int ot = 0; ot < 4; ot++) {
                    f16x8 bf = *(const f16x8*)(wgt + (size_t)(og*64 + ot*16 + col)*CC + ck*32 + grp*8);
                    acc[ot] = __builtin_amdgcn_mfma_f32_16x16x32_f16(af, bf, acc[ot], 0, 0, 0);
                }
            }
            int iw = i0 + ibase + grp * 4;
            #pragma unroll
            for (int ot = 0; ot < 4; ot++) {
                int o = og*64 + ot*16 + col;
                float bo = bv[o];
                union { _Float16 h[4]; uint2 u; } pk;
                pk.h[0] = (_Float16)(acc[ot][0] + bo);
                pk.h[1] = (_Float16)(acc[ot][1] + bo);
                pk.h[2] = (_Float16)(acc[ot][2] + bo);
                pk.h[3] = (_Float16)(acc[ot][3] + bo);
                *(uint2*)(outp + (size_t)o*NN + iw) = pk.u;
            }
        }
    }
}

// ------------- Kernel 3: flash attention -------------
// 32x32x16 QK (operand-symmetric c-assignment -> true k-map cancels) gives
// S[j][q] in the m101-verified C layout: lane owns q=lane&31, 16 j's.
// Softmax per-lane scalar; cross-half combine via __shfl_xor(.,32) (proven).
// P -> per-wave LDS tile; PV via proven 16x16x32 cancellation pattern;
// O in m89-verified C layout. Double-buffered K/V staging (round-4 proven).
#define STAGE_K(tt, bb) do { int _j = jlo + (tt)*CH; _Pragma("unroll") \
    for (int e = 0; e < 4; e++) gload16(kb + (size_t)_j*CC + koff[e], &bufK[bb][(4*w + e)*512]); } while (0)
#define STAGE_V(tt, bb) do { int _j = jlo + (tt)*CH; _Pragma("unroll") \
    for (int e = 0; e < 4; e++) gload16(vb + voff[e] + _j, &bufV[bb][(4*w + e)*512]); } while (0)

__global__ __launch_bounds__(256, 2) void attn_kernel(
    const unsigned short* __restrict__ qT,
    const unsigned short* __restrict__ kT,
    const unsigned short* __restrict__ vC,
    unsigned short* __restrict__ pO,
    float2* __restrict__ ml)
{
    int qt = blockIdx.x, s = blockIdx.y, b = blockIdx.z;
    int tid = threadIdx.x, w = tid >> 6, lane = tid & 63;
    int l31 = lane & 31, hi = lane >> 5;
    int col = lane & 15, grp = lane >> 4;
    int q0 = qt * QTILE + w * 32;
    int jlo = s * JBLK;

    __shared__ __align__(16) unsigned short bufK[2][8192];   // 2 x 16 KB
    __shared__ __align__(16) unsigned short bufV[2][8192];   // 2 x 16 KB
    __shared__ __align__(16) unsigned short plds[4 * 1280];  // 4 waves x 32q x 40sh (10 KB)

    const unsigned short* qb = qT + (size_t)b * NN * CC;
    const unsigned short* kb = kT + (size_t)b * NN * CC;
    const unsigned short* vb = vC + (size_t)b * CC * NN;

    // Q fragment: (lane,e) -> c = ck*16 + hi*8 + e  (same assignment as K below)
    f16x8 qf[16];
    #pragma unroll
    for (int ck = 0; ck < 16; ck++)
        qf[ck] = *(const f16x8*)(qb + (size_t)(q0 + l31)*CC + ck*16 + hi*8);

    int koff[4], voff[4];
    #pragma unroll
    for (int e = 0; e < 4; e++) {
        int blk = (4*w + e)*64 + lane;
        int kj = blk >> 5, kcb = blk & 31;
        koff[e] = kj*CC + ((kcb ^ (kj & 7)) * 8);
        int vc = blk >> 2, vcb = blk & 3;
        voff[e] = vc*NN + ((vcb ^ ((vc >> 1) & 3)) * 8);
    }
    int kru = l31 * 512;     // K row byte base (row = j = l31)
    int kx  = l31 & 7;       // K row XOR
    int vrb = col*64 + ((grp ^ ((col >> 1) & 3)) << 4);   // V read (row c=ct*16+col)
    char* pw  = (char*)plds + w*2560 + l31*80 + 8*hi;     // P write base (row q=l31)
    const char* prd = (const char*)plds + w*2560;          // P read base

    f32x4 O0[16], O1[16];
    #pragma unroll
    for (int ct = 0; ct < 16; ct++) {
        O0[ct] = (f32x4){0.f,0.f,0.f,0.f};
        O1[ct] = (f32x4){0.f,0.f,0.f,0.f};
    }
    float m = -1e30f, l = 0.f;

    STAGE_K(0, 0);
    STAGE_V(0, 0);
    __syncthreads();

    for (int t = 0; t < NT; t++) {
        int cur = t & 1;
        if (t + 1 < NT) {
            STAGE_K(t + 1, cur ^ 1);
            STAGE_V(t + 1, cur ^ 1);
        }
        const char* kbase = (const char*)&bufK[cur][0];
        const char* vbase = (const char*)&bufV[cur][0];

        // QK: S[j][q]; K fragment (lane,e) -> c = ck*16 + hi*8 + e (== Q's map)
        f32x16 S;
        #pragma unroll
        for (int r = 0; r < 16; r++) S[r] = 0.f;
        __builtin_amdgcn_s_setprio(1);
        #pragma unroll
        for (int ck = 0; ck < 16; ck++) {
            f16x8 kf = *(const f16x8*)(kbase + kru + ((((ck*2) | hi) ^ kx) << 4));
            S = __builtin_amdgcn_mfma_f32_32x32x16_f16(kf, qf[ck], S, 0, 0, 0);
        }
        __builtin_amdgcn_s_setprio(0);

        // per-lane softmax over own 16 j; combine with partner half via shfl_xor 32
        float x0 = fmaxf(fmaxf(S[0], S[1]), fmaxf(S[2], S[3]));
        float x1 = fmaxf(fmaxf(S[4], S[5]), fmaxf(S[6], S[7]));
        float x2 = fmaxf(fmaxf(S[8], S[9]), fmaxf(S[10], S[11]));
        float x3 = fmaxf(fmaxf(S[12], S[13]), fmaxf(S[14], S[15]));
        float mh = fmaxf(fmaxf(x0, x1), fmaxf(x2, x3));
        float mx = fmaxf(mh, __shfl_xor(mh, 32));

        // defer-max: rescale only when max grew by > 8 (exp2 domain)
        if (!__all(mx <= m + 8.f)) {
            float mn = fmaxf(m, mx);
            float f = exp2f(m - mn);
            m = mn;
            l *= f;
            float fq0 = __shfl(f, col);
            float fq1 = __shfl(f, 16 + col);
            #pragma unroll
            for (int ct = 0; ct < 16; ct++) { O0[ct] *= fq0; O1[ct] *= fq1; }
        }

        #pragma unroll
        for (int r = 0; r < 16; r++) S[r] = exp2f(S[r] - m);
        float ps = (((S[0]+S[1]) + (S[2]+S[3])) + ((S[4]+S[5]) + (S[6]+S[7])))
                 + (((S[8]+S[9]) + (S[10]+S[11])) + ((S[12]+S[13]) + (S[14]+S[15])));
        l += ps + __shfl_xor(ps, 32);

        // P -> LDS: own j's only (C-layout row formula j=(r&3)+8*(r>>2)+4*hi)
        {
            unsigned* pr = (unsigned*)pw;
            pr[0]  = pkh2(S[0],  S[1]);   pr[1]  = pkh2(S[2],  S[3]);
            pr[4]  = pkh2(S[4],  S[5]);   pr[5]  = pkh2(S[6],  S[7]);
            pr[8]  = pkh2(S[8],  S[9]);   pr[9]  = pkh2(S[10], S[11]);
            pr[12] = pkh2(S[12], S[13]);  pr[13] = pkh2(S[14], S[15]);
        }
        asm volatile("s_waitcnt lgkmcnt(0)" ::: "memory");
        __builtin_amdgcn_sched_barrier(0);

        // PV via 16x16x32: both fragments (lane,e) -> j = grp*8 + e (cancels)
        f16x8 y0 = *(const f16x8*)(prd + col*80 + grp*16);
        f16x8 y1 = *(const f16x8*)(prd + (16 + col)*80 + grp*16);
        __builtin_amdgcn_s_setprio(1);
        #pragma unroll
        for (int ct = 0; ct < 16; ct++) {
            f16x8 xf = *(const f16x8*)(vbase + ct*1024 + vrb);
            O0[ct] = __builtin_amdgcn_mfma_f32_16x16x32_f16(xf, y0, O0[ct], 0, 0, 0);
            O1[ct] = __builtin_amdgcn_mfma_f32_16x16x32_f16(xf, y1, O1[ct], 0, 0, 0);
        }
        __builtin_amdgcn_s_setprio(0);
        __syncthreads();
    }

    // epilogue: O C-layout (m89): q = qh*16+col, c = ct*16 + grp*4 + r
    float inv = 1.f / l;
    float iq0 = __shfl(inv, col);
    float iq1 = __shfl(inv, 16 + col);
    unsigned short* po = pO + ((size_t)(s*BB + b)*NN + q0) * CC;
    #pragma unroll
    for (int ct = 0; ct < 16; ct++) {
        int c = ct*16 + grp*4;
        *(unsigned*)(po + (size_t)col*CC + c)            = pkh2(O0[ct][0]*iq0, O0[ct][1]*iq0);
        *(unsigned*)(po + (size_t)col*CC + c + 2)        = pkh2(O0[ct][2]*iq0, O0[ct][3]*iq0);
        *(unsigned*)(po + (size_t)(16 + col)*CC + c)     = pkh2(O1[ct][0]*iq1, O1[ct][1]*iq1);
        *(unsigned*)(po + (size_t)(16 + col)*CC + c + 2) = pkh2(O1[ct][2]*iq1, O1[ct][3]*iq1);
    }
    if (lane < 32)
        ml[(size_t)(s*BB + b)*NN + q0 + lane] = make_float2(m, l);
}

// ------------- Kernel 3b: merge JSPLIT partials -------------
__global__ __launch_bounds__(256) void attn_merge_kernel(
    const unsigned short* __restrict__ pO, const float2* __restrict__ ml,
    unsigned short* __restrict__ aT)
{
    int t = threadIdx.x;
    int qrow = blockIdx.x * 16 + (t >> 4);   // b*NN + q
    int c0 = (t & 15) * 16;
    float M = -1e30f;
    float m8[JSPLIT], l8[JSPLIT];
    #pragma unroll
    for (int s = 0; s < JSPLIT; s++) {
        float2 v = ml[(size_t)s*BB*NN + qrow];
        m8[s] = v.x; l8[s] = v.y;
        M = fmaxf(M, v.x);
    }
    float W = 0.f, wt[JSPLIT];
    #pragma unroll
    for (int s = 0; s < JSPLIT; s++) { wt[s] = l8[s] * exp2f(m8[s] - M); W += wt[s]; }
    float iW = 1.f / W;
    float acc[16];
    #pragma unroll
    for (int e = 0; e < 16; e++) acc[e] = 0.f;
    #pragma unroll
    for (int s = 0; s < JSPLIT; s++) {
        const unsigned short* p = pO + ((size_t)s*BB*NN + qrow)*CC + c0;
        f16x8 a0 = *(const f16x8*)p;
        f16x8 a1 = *(const f16x8*)(p + 8);
        float ws = wt[s] * iW;
        #pragma unroll
        for (int e = 0; e < 8; e++) {
            acc[e]     += ws * (float)a0[e];
            acc[e + 8] += ws * (float)a1[e];
        }
    }
    union { _Float16 h[8]; uint4 u; } o0, o1;
    #pragma unroll
    for (int e = 0; e < 8; e++) { o0.h[e] = (_Float16)acc[e]; o1.h[e] = (_Float16)acc[e+8]; }
    unsigned short* dst = aT + (size_t)qrow*CC + c0;
    *(uint4*)dst = o0.u;
    *(uint4*)(dst + 8) = o1.u;
}

// ------------- Kernel 4: output projection + bias + residual (fp32 out) -------------
__global__ __launch_bounds__(256) void proj_out_kernel(
    const unsigned short* __restrict__ aT,
    const unsigned short* __restrict__ wp16, const float* __restrict__ bp,
    const float* __restrict__ x, float* __restrict__ out)
{
    int b = blockIdx.z;
    int i0 = blockIdx.x * 64, o0 = blockIdx.y * 64;
    int lane = threadIdx.x & 63, wid = threadIdx.x >> 6;
    int col = lane & 15, grp = lane >> 4;
    int ibase = i0 + wid * 16;
    const unsigned short* ab = aT + (size_t)b*NN*CC;
    f32x4 acc[4];
    for (int ot = 0; ot < 4; ot++) acc[ot] = (f32x4){0.f,0.f,0.f,0.f};
    for (int ck = 0; ck < 8; ck++) {
        f16x8 af = *(const f16x8*)(ab + (size_t)(ibase + col)*CC + ck*32 + grp*8);
        for (int ot = 0; ot < 4; ot++) {
            f16x8 bf = *(const f16x8*)(wp16 + (size_t)(o0 + ot*16 + col)*CC + ck*32 + grp*8);
            acc[ot] = __builtin_amdgcn_mfma_f32_16x16x32_f16(af, bf, acc[ot], 0, 0, 0);
        }
    }
    int iw = ibase + grp * 4;
    for (int ot = 0; ot < 4; ot++) {
        int o = o0 + ot*16 + col;
        float bo = bp[o];
        size_t base = (size_t)b*CC*NN + (size_t)o*NN + iw;
        float4 x4 = *(const float4*)(x + base);
        float4 r;
        r.x = x4.x + acc[ot][0] + bo;
        r.y = x4.y + acc[ot][1] + bo;
        r.z = x4.z + acc[ot][2] + bo;
        r.w = x4.w + acc[ot][3] + bo;
        *(float4*)(out + base) = r;
    }
}

extern "C" void kernel_launch(void* const* d_in, const int* in_sizes, int n_in,
                              void* d_out, int out_size, void* d_ws, size_t ws_size,
                              hipStream_t stream) {
    const float* x  = (const float*)d_in[0];
    const float* gs = (const float*)d_in[1];
    const float* gb = (const float*)d_in[2];
    const float* wq = (const float*)d_in[3];
    const float* bq = (const float*)d_in[4];
    const float* wk = (const float*)d_in[5];
    const float* bk = (const float*)d_in[6];
    const float* wv = (const float*)d_in[7];
    const float* bv = (const float*)d_in[8];
    const float* wp = (const float*)d_in[9];
    const float* bp = (const float*)d_in[10];
    float* out = (float*)d_out;

    char* ws = (char*)d_ws;
    const size_t sz = (size_t)BB * NN * CC * sizeof(unsigned short);   // 4 MB
    unsigned short* qT  = (unsigned short*)(ws + sz);
    unsigned short* kT  = (unsigned short*)(ws + 2*sz);
    unsigned short* vC  = (unsigned short*)(ws + 3*sz);
    unsigned short* aT  = (unsigned short*)(ws + 4*sz);
    unsigned short* w16 = (unsigned short*)(ws + 5*sz);                 // 512 KB
    float2* part        = (float2*)(ws + 5*sz + 512*1024);              // 2 KB
    float2* ml          = (float2*)(ws + 5*sz + 768*1024);              // 512 KB
    unsigned short* pO  = (unsigned short*)(ws + 5*sz + 1280*1024);     // 32 MB

    prep_w16_kernel<<<dim3(CC*CC/4/256, 4), 256, 0, stream>>>(wq, wk, wv, wp, w16);
    gn_part_kernel<<<dim3(GG, 4, BB), 256, 0, stream>>>(x, part);
    proj_qkv_kernel<<<dim3(NN/32, BB), 256, 0, stream>>>(x, gs, gb, part, w16,
                                                         bq, bk, bv, qT, kT, vC);
    attn_kernel<<<dim3(NN/QTILE, JSPLIT, BB), 256, 0, stream>>>(qT, kT, vC, pO, ml);
    attn_merge_kernel<<<dim3(BB*NN/16), 256, 0, stream>>>(pO, ml, aT);
    proj_out_kernel<<<dim3(NN/64, CC/64, BB), 256, 0, stream>>>(aT, w16 + 3*CC*CC, bp, x, out);
}